// Round 4
// baseline (350.073 us; speedup 1.0000x reference)
//
#include <hip/hip_runtime.h>

#define Bb 8
#define Nn 8192
#define Hh 256
#define NUP 2048
#define NDOWN (Nn - NUP)
#define MM 5
#define EPB (NDOWN * MM)   // edges per batch = 30720
#define KP 288             // padded K for the feat GEMM (256 h + sl,score,1,pad)
#define LDA 36             // LDS row stride (bf16) for A/B tiles

typedef short v8s __attribute__((ext_vector_type(8)));
typedef float v4f __attribute__((ext_vector_type(4)));

#define INFKEY 0x7F800000FFFFFFFFull

// fp32 -> bf16 round-to-nearest-even
__device__ __forceinline__ unsigned short bfc(float f) {
    unsigned u = __float_as_uint(f);
    return (unsigned short)((u + 0x7FFFu + ((u >> 16) & 1u)) >> 16);
}

// Find the bin (descending order) where the kth-largest element lands.
template <int NB>
__device__ void find_kth_bin(const int* hist, int kth, int tid,
                             int* wsumA, int* res, int* out_bin, int* out_cntgt) {
    constexpr int PER = NB / 1024;
    int ln = tid & 63, wv = tid >> 6;
    int b0 = NB - 1 - PER * tid;
    int c0 = hist[b0];
    int c1 = (PER == 2) ? hist[b0 - 1] : 0;
    int tot = c0 + c1;
    int x = tot;
    #pragma unroll
    for (int off = 1; off < 64; off <<= 1) {
        int y = __shfl_up(x, off);
        if (ln >= off) x += y;
    }
    if (ln == 63) wsumA[wv] = x;
    __syncthreads();
    int wbase = 0;
    for (int w = 0; w < wv; w++) wbase += wsumA[w];
    int excl = wbase + x - tot;
    if (excl < kth && excl + c0 >= kth) { res[0] = b0; res[1] = excl; }
    else if (PER == 2 && excl + c0 < kth && excl + c0 + c1 >= kth) { res[0] = b0 - 1; res[1] = excl + c0; }
    __syncthreads();
    *out_bin = res[0];
    *out_cntgt = res[1];
}

// Kernel A: exact top-NUP selection via 3-level radix select, fused compaction
// (ups -> upc, downs -> dnc, both in node order) + up_local inverse map + deg
// zeroing.
__global__ __launch_bounds__(1024) void select_kernel(
        const float* __restrict__ scores, const float* __restrict__ sl,
        int* __restrict__ mask, float4* __restrict__ upc,
        float4* __restrict__ dnc, int* __restrict__ up_local,
        int* __restrict__ deg) {
    int b = blockIdx.x;
    int tid = threadIdx.x;
    int ln = tid & 63, wv = tid >> 6;
    __shared__ int hist[2048];
    __shared__ int wsumA[16], wsumB[16];
    __shared__ int res[2];
    __shared__ int sbase[2];
    const float* s = scores + (size_t)b * Nn;

    deg[b * NUP + tid] = 0;
    deg[b * NUP + 1024 + tid] = 0;

    hist[tid] = 0; hist[tid + 1024] = 0;
    __syncthreads();
    for (int t = tid; t < Nn; t += 1024)
        atomicAdd(&hist[__float_as_uint(s[t]) >> 21], 1);
    __syncthreads();
    int B1, gt1;
    find_kth_bin<2048>(hist, NUP, tid, wsumA, res, &B1, &gt1);
    int slots1 = NUP - gt1;

    hist[tid] = 0; hist[tid + 1024] = 0;
    __syncthreads();
    for (int t = tid; t < Nn; t += 1024) {
        unsigned u = __float_as_uint(s[t]);
        if ((int)(u >> 21) == B1) atomicAdd(&hist[(u >> 10) & 0x7FF], 1);
    }
    __syncthreads();
    int B2, gt2;
    find_kth_bin<2048>(hist, slots1, tid, wsumA, res, &B2, &gt2);
    int slots2 = slots1 - gt2;
    unsigned hi22 = ((unsigned)B1 << 11) | (unsigned)B2;

    hist[tid] = 0; hist[tid + 1024] = 0;
    __syncthreads();
    for (int t = tid; t < Nn; t += 1024) {
        unsigned u = __float_as_uint(s[t]);
        if ((u >> 10) == hi22) atomicAdd(&hist[u & 0x3FF], 1);
    }
    __syncthreads();
    int B3, gt3;
    find_kth_bin<1024>(hist, slots2, tid, wsumA, res, &B3, &gt3);
    int slots_eq = slots2 - gt3;
    unsigned T = (hi22 << 10) | (unsigned)B3;

    if (tid == 0) { sbase[0] = 0; sbase[1] = 0; }
    __syncthreads();
    for (int t0 = 0; t0 < Nn; t0 += 1024) {
        int node = t0 + tid;
        int g = b * Nn + node;
        unsigned u = __float_as_uint(s[node]);
        bool eq = (u == T);
        unsigned long long bal = __ballot(eq);
        unsigned long long lmask = (1ull << ln) - 1ull;
        int pre = __popcll(bal & lmask);
        if (ln == 0) wsumA[wv] = __popcll(bal);
        __syncthreads();
        int eqbase = sbase[0];
        for (int w = 0; w < wv; w++) eqbase += wsumA[w];
        bool up = (u > T) || (eq && (eqbase + pre) < slots_eq);
        unsigned long long bal2 = __ballot(up);
        int pre2 = __popcll(bal2 & lmask);
        if (ln == 0) wsumB[wv] = __popcll(bal2);
        __syncthreads();
        int upbase = sbase[1];
        for (int w = 0; w < wv; w++) upbase += wsumB[w];
        float4 c;
        c.x = sl[(size_t)g * 3 + 0];
        c.y = sl[(size_t)g * 3 + 1];
        c.z = sl[(size_t)g * 3 + 2];
        c.w = __int_as_float(node);
        if (up) {
            upc[b * NUP + upbase + pre2] = c;
            up_local[g] = upbase + pre2;
        } else {
            dnc[b * NDOWN + node - (upbase + pre2)] = c;
        }
        mask[g] = up ? 1 : 0;
        __syncthreads();
        if (tid == 0) {
            int se = 0, su = 0;
            for (int w = 0; w < 16; w++) { se += wsumA[w]; su += wsumB[w]; }
            sbase[0] += se; sbase[1] += su;
        }
        __syncthreads();
    }
}

// Kernel C: exact 5-NN, brute force. 512 threads = 64 downs (lanes) x 8
// candidate subsets (waves). Ups streamed through LDS in 4 pages of 512;
// within a wave the staged read is lane-uniform -> LDS broadcast (no
// conflicts, one access/wave-iter). Early-out threshold reject keeps the
// common path ~10 VALU ops. Perfectly uniform work, 10 barriers/block.
// u64 (d2<<32|id) keys = exact (d2,idx) match to ref top_k tie-breaking.
__global__ __launch_bounds__(512) void knn_brute(
        const float4* __restrict__ upc, const float4* __restrict__ dnc,
        const int* __restrict__ up_local, int* __restrict__ knn,
        int* __restrict__ deg) {
    int b = blockIdx.y;
    int tid = threadIdx.x;
    int sub = tid >> 6, dn = tid & 63;   // 8 subs x 64 downs
    __shared__ float4 stage[512];
    __shared__ unsigned long long part[40 * 64];  // [(sub*5+m)*64 + dn]

    float4 d = dnc[b * NDOWN + blockIdx.x * 64 + dn];
    float xd = d.x, yd = d.y, zd = d.z;
    int node = __float_as_int(d.w);

    unsigned long long bd[MM];
    #pragma unroll
    for (int m = 0; m < MM; m++) bd[m] = INFKEY;

    auto ins = [&](unsigned long long* L, unsigned long long cand) {
        #pragma unroll
        for (int m = 0; m < MM; m++) {
            bool lt = cand < L[m];
            unsigned long long lo = lt ? cand : L[m];
            unsigned long long hi = lt ? L[m] : cand;
            L[m] = lo; cand = hi;
        }
    };

    const float4* U = upc + b * NUP;
    for (int c0 = 0; c0 < NUP; c0 += 512) {
        __syncthreads();   // previous page fully consumed
        stage[tid] = U[c0 + tid];
        __syncthreads();
        unsigned thr_ = (unsigned)(bd[MM - 1] >> 32);
        int j0 = sub * 64, j1 = j0 + 64;
        for (int j = j0; j < j1; ++j) {
            float4 c = stage[j];
            float dx = c.x - xd, dy = c.y - yd, dz = c.z - zd;
            float d2 = fmaf(dx, dx, fmaf(dy, dy, dz * dz));
            unsigned du = __float_as_uint(d2);
            if (du <= thr_) {
                unsigned long long key = ((unsigned long long)du << 32) |
                                         (unsigned long long)(unsigned)__float_as_int(c.w);
                if (key < bd[MM - 1]) {
                    ins(bd, key);
                    thr_ = (unsigned)(bd[MM - 1] >> 32);
                }
            }
        }
    }

    // final merge + outputs
    __syncthreads();
    #pragma unroll
    for (int m = 0; m < MM; m++) part[(sub * MM + m) * 64 + dn] = bd[m];
    __syncthreads();
    if (sub == 0) {
        unsigned long long fin[MM];
        #pragma unroll
        for (int m = 0; m < MM; m++) fin[m] = 0xFFFFFFFFFFFFFFFFull;
        #pragma unroll
        for (int l = 0; l < 8; l++)
            #pragma unroll
            for (int m = 0; m < MM; m++) ins(fin, part[(l * MM + m) * 64 + dn]);
        int g = b * Nn + node;
        #pragma unroll
        for (int m = 0; m < MM; m++) {
            int nid = (int)(unsigned)(fin[m] & 0xFFFFFFFFull);
            knn[g * MM + m] = nid;
            atomicAdd(&deg[b * NUP + up_local[b * Nn + nid]], 1);
        }
    }
}

// Kernel W: Wt[n][k] = bf16 of W-ext^T.
__global__ void wt_kernel(const float* __restrict__ W, const float* __restrict__ bias,
                          unsigned short* __restrict__ Wt) {
    int n = blockIdx.x;
    int k = threadIdx.x;
    Wt[n * KP + k] = bfc(W[(size_t)k * Hh + n]);
    if (k < KP - 256) {
        int kk = 256 + k;
        unsigned short v = 0;
        if (kk < 260)       v = bfc(W[(size_t)kk * Hh + n]);
        else if (kk == 260) v = bfc(bias[n]);
        Wt[n * KP + kk] = v;
    }
}

// Kernel B: feat GEMM via bf16 MFMA. C[128m x 128n] per block, 4 waves of 64x64.
__global__ void feat_mfma(const float* __restrict__ h, const float* __restrict__ sl,
                          const float* __restrict__ sc, const unsigned short* __restrict__ Wt,
                          float* __restrict__ out) {
    int b = blockIdx.z;
    int m0 = blockIdx.x * 128;
    int n0 = blockIdx.y * 128;
    int tid = threadIdx.x;
    __shared__ unsigned short Al[128 * LDA];
    __shared__ unsigned short Bl[128 * LDA];
    int wid = tid >> 6, lane = tid & 63;
    int wm = (wid & 1) * 64, wn = (wid >> 1) * 64;
    int lm = lane & 15, quad = lane >> 4;
    v4f acc[4][4];
    #pragma unroll
    for (int i = 0; i < 4; i++)
        #pragma unroll
        for (int j = 0; j < 4; j++)
            acc[i][j] = (v4f){0.f, 0.f, 0.f, 0.f};
    const float* Ab = h + ((size_t)b * Nn + m0) * Hh;
    for (int t = 0; t < 9; t++) {
        int k0 = t * 32;
        __syncthreads();
        if (t < 8) {
            #pragma unroll
            for (int q = 0; q < 4; q++) {
                int e = q * 256 + tid;
                int row = e >> 3, kq = e & 7;
                float4 v = *(const float4*)(Ab + (size_t)row * Hh + k0 + kq * 4);
                ushort4 o = make_ushort4(bfc(v.x), bfc(v.y), bfc(v.z), bfc(v.w));
                *(ushort4*)(Al + row * LDA + kq * 4) = o;
            }
        } else if (tid < 128) {
            int row = tid;
            int g = b * Nn + m0 + row;
            unsigned short r[32];
            #pragma unroll
            for (int k = 0; k < 32; k++) r[k] = 0;
            r[0] = bfc(sl[(size_t)g * 3 + 0]);
            r[1] = bfc(sl[(size_t)g * 3 + 1]);
            r[2] = bfc(sl[(size_t)g * 3 + 2]);
            r[3] = bfc(sc[g]);
            r[4] = 0x3F80;  // 1.0 (bias column)
            #pragma unroll
            for (int q = 0; q < 8; q++)
                *(ushort4*)(Al + row * LDA + q * 4) =
                    make_ushort4(r[q * 4], r[q * 4 + 1], r[q * 4 + 2], r[q * 4 + 3]);
        }
        #pragma unroll
        for (int q = 0; q < 4; q++) {
            int e = q * 256 + tid;
            int n = e >> 3, kq = e & 7;
            ushort4 v = *(const ushort4*)(Wt + (size_t)(n0 + n) * KP + k0 + kq * 4);
            *(ushort4*)(Bl + n * LDA + kq * 4) = v;
        }
        __syncthreads();
        v8s af[4], bfr[4];
        #pragma unroll
        for (int i = 0; i < 4; i++)
            af[i] = *(const v8s*)(Al + (wm + i * 16 + lm) * LDA + quad * 8);
        #pragma unroll
        for (int j = 0; j < 4; j++)
            bfr[j] = *(const v8s*)(Bl + (wn + j * 16 + lm) * LDA + quad * 8);
        #pragma unroll
        for (int i = 0; i < 4; i++)
            #pragma unroll
            for (int j = 0; j < 4; j++)
                acc[i][j] = __builtin_amdgcn_mfma_f32_16x16x32_bf16(af[i], bfr[j], acc[i][j], 0, 0, 0);
    }
    #pragma unroll
    for (int i = 0; i < 4; i++) {
        #pragma unroll
        for (int r = 0; r < 4; r++) {
            int row = m0 + wm + i * 16 + quad * 4 + r;
            size_t base = ((size_t)b * Nn + row) * Hh + n0 + wn + lm;
            #pragma unroll
            for (int j = 0; j < 4; j++)
                out[base + j * 16] = acc[i][j][r];
        }
    }
}

// CSR build: per-batch exclusive scan of deg -> rowptr (+ cursor copy).
__global__ __launch_bounds__(1024) void csr_scan(const int* __restrict__ deg,
                                                 int* __restrict__ rowptr,
                                                 int* __restrict__ cursor) {
    int b = blockIdx.x;
    int tid = threadIdx.x;
    int ln = tid & 63, wv = tid >> 6;
    __shared__ int wsum[16];
    int d0 = deg[b * NUP + 2 * tid], d1 = deg[b * NUP + 2 * tid + 1];
    int s = d0 + d1;
    int x = s;
    #pragma unroll
    for (int off = 1; off < 64; off <<= 1) {
        int y = __shfl_up(x, off);
        if (ln >= off) x += y;
    }
    if (ln == 63) wsum[wv] = x;
    __syncthreads();
    int base = 0;
    for (int w = 0; w < wv; w++) base += wsum[w];
    int excl = base + x - s;
    rowptr[b * (NUP + 1) + 2 * tid] = excl;
    rowptr[b * (NUP + 1) + 2 * tid + 1] = excl + d0;
    cursor[b * NUP + 2 * tid] = excl;
    cursor[b * NUP + 2 * tid + 1] = excl + d0;
    if (tid == 1023) rowptr[b * (NUP + 1) + NUP] = excl + s;
}

// CSR build: fill edge array (src = batch-local down node id).
__global__ void csr_fill(const int* __restrict__ mask, const int* __restrict__ knn,
                         const int* __restrict__ up_local, int* __restrict__ cursor,
                         int* __restrict__ edges) {
    int b = blockIdx.y;
    int i = blockIdx.x * 256 + threadIdx.x;
    int g = b * Nn + i;
    if (mask[g]) return;
    #pragma unroll
    for (int m = 0; m < MM; m++) {
        int un = knn[g * MM + m];
        int slot = atomicAdd(&cursor[b * NUP + up_local[b * Nn + un]], 1);
        edges[b * EPB + slot] = i;
    }
}

// Kernel D: gather-max. One wave per up node; lanes own 4 cols (float4).
__global__ void gather_kernel(const float4* __restrict__ upc, const int* __restrict__ rowptr,
                              const int* __restrict__ edges, float* __restrict__ out) {
    int b = blockIdx.y;
    int u = blockIdx.x * 4 + (threadIdx.x >> 6);
    int lane = threadIdx.x & 63;
    int node = __float_as_int(upc[b * NUP + u].w);
    int start = rowptr[b * (NUP + 1) + u];
    int end   = rowptr[b * (NUP + 1) + u + 1];
    const int* eb = edges + b * EPB;
    size_t rowbase = (size_t)b * Nn * Hh + (size_t)(lane << 2);
    float4 a0 = make_float4(-3.4e38f, -3.4e38f, -3.4e38f, -3.4e38f);
    float4 a1 = a0;
    int e = start;
    for (; e + 2 <= end; e += 2) {
        int s0 = eb[e], s1 = eb[e + 1];
        float4 v0 = *(const float4*)(out + rowbase + (size_t)s0 * Hh);
        float4 v1 = *(const float4*)(out + rowbase + (size_t)s1 * Hh);
        a0.x = fmaxf(a0.x, v0.x); a0.y = fmaxf(a0.y, v0.y);
        a0.z = fmaxf(a0.z, v0.z); a0.w = fmaxf(a0.w, v0.w);
        a1.x = fmaxf(a1.x, v1.x); a1.y = fmaxf(a1.y, v1.y);
        a1.z = fmaxf(a1.z, v1.z); a1.w = fmaxf(a1.w, v1.w);
    }
    if (e < end) {
        int s0 = eb[e];
        float4 v0 = *(const float4*)(out + rowbase + (size_t)s0 * Hh);
        a0.x = fmaxf(a0.x, v0.x); a0.y = fmaxf(a0.y, v0.y);
        a0.z = fmaxf(a0.z, v0.z); a0.w = fmaxf(a0.w, v0.w);
    }
    float4 r;
    r.x = fmaxf(a0.x, a1.x); r.y = fmaxf(a0.y, a1.y);
    r.z = fmaxf(a0.z, a1.z); r.w = fmaxf(a0.w, a1.w);
    if (start == end) r = make_float4(0.f, 0.f, 0.f, 0.f);
    *(float4*)(out + rowbase + (size_t)node * Hh) = r;
}

// Kernel E: zero down rows, write mask tail.
__global__ void finalize_kernel(const int* __restrict__ mask, float* __restrict__ out) {
    int b = blockIdx.y;
    int node = blockIdx.x * 4 + (threadIdx.x >> 6);
    int g = b * Nn + node;
    int lane = threadIdx.x & 63;
    bool up = mask[g] != 0;
    if (!up)
        *(float4*)(out + (size_t)g * Hh + (lane << 2)) = make_float4(0.f, 0.f, 0.f, 0.f);
    if (lane == 0) out[(size_t)Bb * Nn * Hh + g] = up ? 1.0f : 0.0f;
}

extern "C" void kernel_launch(void* const* d_in, const int* in_sizes, int n_in,
                              void* d_out, int out_size, void* d_ws, size_t ws_size,
                              hipStream_t stream) {
    const float* h    = (const float*)d_in[0];
    const float* sl   = (const float*)d_in[1];
    const float* sc   = (const float*)d_in[2];
    const float* W    = (const float*)d_in[3];
    const float* bias = (const float*)d_in[4];

    char* ws = (char*)d_ws;
    int* mask = (int*)ws;                 ws += (size_t)Bb * Nn * sizeof(int);
    int* knn  = (int*)ws;                 ws += (size_t)Bb * Nn * MM * sizeof(int);
    float4* upc = (float4*)ws;            ws += (size_t)Bb * NUP * sizeof(float4);
    float4* dnc = (float4*)ws;            ws += (size_t)Bb * NDOWN * sizeof(float4);
    unsigned short* Wt = (unsigned short*)ws; ws += (size_t)Hh * KP * sizeof(unsigned short);
    int* up_local = (int*)ws;             ws += (size_t)Bb * Nn * sizeof(int);
    int* deg = (int*)ws;                  ws += (size_t)Bb * NUP * sizeof(int);
    int* cursor = (int*)ws;               ws += (size_t)Bb * NUP * sizeof(int);
    int* rowptr = (int*)ws;               ws += (size_t)Bb * (NUP + 1) * sizeof(int);
    int* edges = (int*)ws;                // B*EPB ints
    float* outf = (float*)d_out;

    dim3 blk(256);
    select_kernel<<<dim3(Bb), dim3(1024), 0, stream>>>(sc, sl, mask, upc, dnc,
                                                       up_local, deg);
    knn_brute<<<dim3(NDOWN / 64, Bb), dim3(512), 0, stream>>>(upc, dnc,
                                                              up_local, knn, deg);
    csr_scan<<<dim3(Bb), dim3(1024), 0, stream>>>(deg, rowptr, cursor);
    csr_fill<<<dim3(Nn / 256, Bb), blk, 0, stream>>>(mask, knn, up_local, cursor, edges);
    wt_kernel<<<dim3(Hh), blk, 0, stream>>>(W, bias, Wt);
    feat_mfma<<<dim3(Nn / 128, 2, Bb), blk, 0, stream>>>(h, sl, sc, Wt, outf);
    gather_kernel<<<dim3(NUP / 4, Bb), blk, 0, stream>>>(upc, rowptr, edges, outf);
    finalize_kernel<<<dim3(Nn / 4, Bb), blk, 0, stream>>>(mask, outf);
}

// Round 5
// 300.828 us; speedup vs baseline: 1.1637x; 1.1637x over previous
//
#include <hip/hip_runtime.h>

#define Bb 8
#define Nn 8192
#define Hh 256
#define NUP 2048
#define NDOWN (Nn - NUP)
#define MM 5
#define EPB (NDOWN * MM)   // edges per batch = 30720
#define KP 288             // padded K for the feat GEMM (256 h + sl,score,1,pad)
#define LDA 36             // LDS row stride (bf16) for A/B tiles
#define LSTW 17            // padded hit-list stride (u64) to dodge bank conflicts

typedef short v8s __attribute__((ext_vector_type(8)));
typedef float v4f __attribute__((ext_vector_type(4)));

#define INFKEY 0x7F800000FFFFFFFFull

// fp32 -> bf16 round-to-nearest-even
__device__ __forceinline__ unsigned short bfc(float f) {
    unsigned u = __float_as_uint(f);
    return (unsigned short)((u + 0x7FFFu + ((u >> 16) & 1u)) >> 16);
}

// Find the bin (descending order) where the kth-largest element lands.
template <int NB>
__device__ void find_kth_bin(const int* hist, int kth, int tid,
                             int* wsumA, int* res, int* out_bin, int* out_cntgt) {
    constexpr int PER = NB / 1024;
    int ln = tid & 63, wv = tid >> 6;
    int b0 = NB - 1 - PER * tid;
    int c0 = hist[b0];
    int c1 = (PER == 2) ? hist[b0 - 1] : 0;
    int tot = c0 + c1;
    int x = tot;
    #pragma unroll
    for (int off = 1; off < 64; off <<= 1) {
        int y = __shfl_up(x, off);
        if (ln >= off) x += y;
    }
    if (ln == 63) wsumA[wv] = x;
    __syncthreads();
    int wbase = 0;
    for (int w = 0; w < wv; w++) wbase += wsumA[w];
    int excl = wbase + x - tot;
    if (excl < kth && excl + c0 >= kth) { res[0] = b0; res[1] = excl; }
    else if (PER == 2 && excl + c0 < kth && excl + c0 + c1 >= kth) { res[0] = b0 - 1; res[1] = excl + c0; }
    __syncthreads();
    *out_bin = res[0];
    *out_cntgt = res[1];
}

// Kernel A: exact top-NUP selection via 3-level radix select, fused compaction
// (ups -> upc, downs -> dnc, both in node order) + up_local inverse map + deg
// zeroing.
__global__ __launch_bounds__(1024) void select_kernel(
        const float* __restrict__ scores, const float* __restrict__ sl,
        int* __restrict__ mask, float4* __restrict__ upc,
        float4* __restrict__ dnc, int* __restrict__ up_local,
        int* __restrict__ deg) {
    int b = blockIdx.x;
    int tid = threadIdx.x;
    int ln = tid & 63, wv = tid >> 6;
    __shared__ int hist[2048];
    __shared__ int wsumA[16], wsumB[16];
    __shared__ int res[2];
    __shared__ int sbase[2];
    const float* s = scores + (size_t)b * Nn;

    deg[b * NUP + tid] = 0;
    deg[b * NUP + 1024 + tid] = 0;

    hist[tid] = 0; hist[tid + 1024] = 0;
    __syncthreads();
    for (int t = tid; t < Nn; t += 1024)
        atomicAdd(&hist[__float_as_uint(s[t]) >> 21], 1);
    __syncthreads();
    int B1, gt1;
    find_kth_bin<2048>(hist, NUP, tid, wsumA, res, &B1, &gt1);
    int slots1 = NUP - gt1;

    hist[tid] = 0; hist[tid + 1024] = 0;
    __syncthreads();
    for (int t = tid; t < Nn; t += 1024) {
        unsigned u = __float_as_uint(s[t]);
        if ((int)(u >> 21) == B1) atomicAdd(&hist[(u >> 10) & 0x7FF], 1);
    }
    __syncthreads();
    int B2, gt2;
    find_kth_bin<2048>(hist, slots1, tid, wsumA, res, &B2, &gt2);
    int slots2 = slots1 - gt2;
    unsigned hi22 = ((unsigned)B1 << 11) | (unsigned)B2;

    hist[tid] = 0; hist[tid + 1024] = 0;
    __syncthreads();
    for (int t = tid; t < Nn; t += 1024) {
        unsigned u = __float_as_uint(s[t]);
        if ((u >> 10) == hi22) atomicAdd(&hist[u & 0x3FF], 1);
    }
    __syncthreads();
    int B3, gt3;
    find_kth_bin<1024>(hist, slots2, tid, wsumA, res, &B3, &gt3);
    int slots_eq = slots2 - gt3;
    unsigned T = (hi22 << 10) | (unsigned)B3;

    if (tid == 0) { sbase[0] = 0; sbase[1] = 0; }
    __syncthreads();
    for (int t0 = 0; t0 < Nn; t0 += 1024) {
        int node = t0 + tid;
        int g = b * Nn + node;
        unsigned u = __float_as_uint(s[node]);
        bool eq = (u == T);
        unsigned long long bal = __ballot(eq);
        unsigned long long lmask = (1ull << ln) - 1ull;
        int pre = __popcll(bal & lmask);
        if (ln == 0) wsumA[wv] = __popcll(bal);
        __syncthreads();
        int eqbase = sbase[0];
        for (int w = 0; w < wv; w++) eqbase += wsumA[w];
        bool up = (u > T) || (eq && (eqbase + pre) < slots_eq);
        unsigned long long bal2 = __ballot(up);
        int pre2 = __popcll(bal2 & lmask);
        if (ln == 0) wsumB[wv] = __popcll(bal2);
        __syncthreads();
        int upbase = sbase[1];
        for (int w = 0; w < wv; w++) upbase += wsumB[w];
        float4 c;
        c.x = sl[(size_t)g * 3 + 0];
        c.y = sl[(size_t)g * 3 + 1];
        c.z = sl[(size_t)g * 3 + 2];
        c.w = __int_as_float(node);
        if (up) {
            upc[b * NUP + upbase + pre2] = c;
            up_local[g] = upbase + pre2;
        } else {
            dnc[b * NDOWN + node - (upbase + pre2)] = c;
        }
        mask[g] = up ? 1 : 0;
        __syncthreads();
        if (tid == 0) {
            int se = 0, su = 0;
            for (int w = 0; w < 16; w++) { se += wsumA[w]; su += wsumB[w]; }
            sbase[0] += se; sbase[1] += su;
        }
        __syncthreads();
    }
}

// Kernel C: exact 5-NN, brute force, two-phase branchless. 512 threads =
// 64 downs (lanes) x 8 candidate slices (waves); whole up set staged in LDS.
// Phase 1: per-thread 5 smallest d2 VALUES via f32 min/max network (10 VALU,
// branchless -> no wave-divergence, the R4 lesson). Merge 8x5 -> true 5th
// distance thr per down. Phase 2: rescan with tight gate d2<=thr (wave hit
// rate ~16%), hits append (d2,idx) u64 keys to a short per-down LDS list.
// Final: exact sort of the list by (d2,idx) = ref tie-breaking. Phase-1/2
// d2 are bit-identical (same fmaf chain on same staged data), gate is
// inclusive -> ties at thr captured -> exact.
__global__ __launch_bounds__(512) void knn_brute(
        const float4* __restrict__ upc, const float4* __restrict__ dnc,
        const int* __restrict__ up_local, int* __restrict__ knn,
        int* __restrict__ deg) {
    int b = blockIdx.y;
    int tid = threadIdx.x;
    int sub = tid >> 6, dn = tid & 63;   // 8 subs x 64 downs
    __shared__ float4 stage[NUP];                  // 32 KB: whole up set
    __shared__ float sThr[8 * MM * 64];            // 10 KB: phase-1 partials
    __shared__ unsigned long long lst[64 * LSTW];  // 8.5 KB: hit lists
    __shared__ int lcnt[64];

    float4 d = dnc[b * NDOWN + blockIdx.x * 64 + dn];
    float xd = d.x, yd = d.y, zd = d.z;
    int node = __float_as_int(d.w);

    const float4* U = upc + b * NUP;
    #pragma unroll
    for (int q = 0; q < 4; q++) stage[q * 512 + tid] = U[q * 512 + tid];
    if (tid < 64) lcnt[tid] = 0;
    __syncthreads();

    // ---- phase 1: branchless top-5 distances over this thread's 256-slice
    float L[MM];
    #pragma unroll
    for (int m = 0; m < MM; m++) L[m] = 3.4e38f;
    const int j0 = sub * 256;
    #pragma unroll 4
    for (int j = j0; j < j0 + 256; ++j) {
        float4 c = stage[j];
        float dx = c.x - xd, dy = c.y - yd, dz = c.z - zd;
        float d2 = fmaf(dx, dx, fmaf(dy, dy, dz * dz));
        #pragma unroll
        for (int m = 0; m < MM; m++) {
            float lo = fminf(d2, L[m]), hi = fmaxf(d2, L[m]);
            L[m] = lo; d2 = hi;
        }
    }
    #pragma unroll
    for (int m = 0; m < MM; m++) sThr[(sub * MM + m) * 64 + dn] = L[m];
    __syncthreads();

    // ---- merge to the true global 5th-smallest distance per down
    if (sub == 0) {
        float F[MM];
        #pragma unroll
        for (int m = 0; m < MM; m++) F[m] = 3.4e38f;
        for (int l = 0; l < 8; l++) {
            #pragma unroll
            for (int m = 0; m < MM; m++) {
                float v = sThr[(l * MM + m) * 64 + dn];
                #pragma unroll
                for (int k = 0; k < MM; k++) {
                    float lo = fminf(v, F[k]), hi = fmaxf(v, F[k]);
                    F[k] = lo; v = hi;
                }
            }
        }
        sThr[dn] = F[MM - 1];
    }
    __syncthreads();
    float thr = sThr[dn];

    // ---- phase 2: tight-gated exact hit collection
    #pragma unroll 4
    for (int j = j0; j < j0 + 256; ++j) {
        float4 c = stage[j];
        float dx = c.x - xd, dy = c.y - yd, dz = c.z - zd;
        float d2 = fmaf(dx, dx, fmaf(dy, dy, dz * dz));
        if (d2 <= thr) {
            unsigned long long key =
                ((unsigned long long)__float_as_uint(d2) << 32) |
                (unsigned long long)(unsigned)__float_as_int(c.w);
            int s = atomicAdd(&lcnt[dn], 1);
            if (s < LSTW - 1) lst[dn * LSTW + s] = key;
        }
    }
    __syncthreads();

    // ---- final: exact (d2,idx) sort of the short list + outputs
    if (sub == 0) {
        unsigned long long fin[MM];
        #pragma unroll
        for (int m = 0; m < MM; m++) fin[m] = 0xFFFFFFFFFFFFFFFFull;
        int n = min(lcnt[dn], LSTW - 1);
        for (int s = 0; s < n; s++) {
            unsigned long long cand = lst[dn * LSTW + s];
            #pragma unroll
            for (int m = 0; m < MM; m++) {
                bool lt = cand < fin[m];
                unsigned long long lo = lt ? cand : fin[m];
                unsigned long long hi = lt ? fin[m] : cand;
                fin[m] = lo; cand = hi;
            }
        }
        int g = b * Nn + node;
        #pragma unroll
        for (int m = 0; m < MM; m++) {
            int nid = (int)(unsigned)(fin[m] & 0xFFFFFFFFull);
            knn[g * MM + m] = nid;
            atomicAdd(&deg[b * NUP + up_local[b * Nn + nid]], 1);
        }
    }
}

// Kernel W: Wt[n][k] = bf16 of W-ext^T.
__global__ void wt_kernel(const float* __restrict__ W, const float* __restrict__ bias,
                          unsigned short* __restrict__ Wt) {
    int n = blockIdx.x;
    int k = threadIdx.x;
    Wt[n * KP + k] = bfc(W[(size_t)k * Hh + n]);
    if (k < KP - 256) {
        int kk = 256 + k;
        unsigned short v = 0;
        if (kk < 260)       v = bfc(W[(size_t)kk * Hh + n]);
        else if (kk == 260) v = bfc(bias[n]);
        Wt[n * KP + kk] = v;
    }
}

// Kernel B: feat GEMM via bf16 MFMA. C[128m x 128n] per block, 4 waves of 64x64.
__global__ void feat_mfma(const float* __restrict__ h, const float* __restrict__ sl,
                          const float* __restrict__ sc, const unsigned short* __restrict__ Wt,
                          float* __restrict__ out) {
    int b = blockIdx.z;
    int m0 = blockIdx.x * 128;
    int n0 = blockIdx.y * 128;
    int tid = threadIdx.x;
    __shared__ unsigned short Al[128 * LDA];
    __shared__ unsigned short Bl[128 * LDA];
    int wid = tid >> 6, lane = tid & 63;
    int wm = (wid & 1) * 64, wn = (wid >> 1) * 64;
    int lm = lane & 15, quad = lane >> 4;
    v4f acc[4][4];
    #pragma unroll
    for (int i = 0; i < 4; i++)
        #pragma unroll
        for (int j = 0; j < 4; j++)
            acc[i][j] = (v4f){0.f, 0.f, 0.f, 0.f};
    const float* Ab = h + ((size_t)b * Nn + m0) * Hh;
    for (int t = 0; t < 9; t++) {
        int k0 = t * 32;
        __syncthreads();
        if (t < 8) {
            #pragma unroll
            for (int q = 0; q < 4; q++) {
                int e = q * 256 + tid;
                int row = e >> 3, kq = e & 7;
                float4 v = *(const float4*)(Ab + (size_t)row * Hh + k0 + kq * 4);
                ushort4 o = make_ushort4(bfc(v.x), bfc(v.y), bfc(v.z), bfc(v.w));
                *(ushort4*)(Al + row * LDA + kq * 4) = o;
            }
        } else if (tid < 128) {
            int row = tid;
            int g = b * Nn + m0 + row;
            unsigned short r[32];
            #pragma unroll
            for (int k = 0; k < 32; k++) r[k] = 0;
            r[0] = bfc(sl[(size_t)g * 3 + 0]);
            r[1] = bfc(sl[(size_t)g * 3 + 1]);
            r[2] = bfc(sl[(size_t)g * 3 + 2]);
            r[3] = bfc(sc[g]);
            r[4] = 0x3F80;  // 1.0 (bias column)
            #pragma unroll
            for (int q = 0; q < 8; q++)
                *(ushort4*)(Al + row * LDA + q * 4) =
                    make_ushort4(r[q * 4], r[q * 4 + 1], r[q * 4 + 2], r[q * 4 + 3]);
        }
        #pragma unroll
        for (int q = 0; q < 4; q++) {
            int e = q * 256 + tid;
            int n = e >> 3, kq = e & 7;
            ushort4 v = *(const ushort4*)(Wt + (size_t)(n0 + n) * KP + k0 + kq * 4);
            *(ushort4*)(Bl + n * LDA + kq * 4) = v;
        }
        __syncthreads();
        v8s af[4], bfr[4];
        #pragma unroll
        for (int i = 0; i < 4; i++)
            af[i] = *(const v8s*)(Al + (wm + i * 16 + lm) * LDA + quad * 8);
        #pragma unroll
        for (int j = 0; j < 4; j++)
            bfr[j] = *(const v8s*)(Bl + (wn + j * 16 + lm) * LDA + quad * 8);
        #pragma unroll
        for (int i = 0; i < 4; i++)
            #pragma unroll
            for (int j = 0; j < 4; j++)
                acc[i][j] = __builtin_amdgcn_mfma_f32_16x16x32_bf16(af[i], bfr[j], acc[i][j], 0, 0, 0);
    }
    #pragma unroll
    for (int i = 0; i < 4; i++) {
        #pragma unroll
        for (int r = 0; r < 4; r++) {
            int row = m0 + wm + i * 16 + quad * 4 + r;
            size_t base = ((size_t)b * Nn + row) * Hh + n0 + wn + lm;
            #pragma unroll
            for (int j = 0; j < 4; j++)
                out[base + j * 16] = acc[i][j][r];
        }
    }
}

// CSR build: per-batch exclusive scan of deg -> rowptr (+ cursor copy).
__global__ __launch_bounds__(1024) void csr_scan(const int* __restrict__ deg,
                                                 int* __restrict__ rowptr,
                                                 int* __restrict__ cursor) {
    int b = blockIdx.x;
    int tid = threadIdx.x;
    int ln = tid & 63, wv = tid >> 6;
    __shared__ int wsum[16];
    int d0 = deg[b * NUP + 2 * tid], d1 = deg[b * NUP + 2 * tid + 1];
    int s = d0 + d1;
    int x = s;
    #pragma unroll
    for (int off = 1; off < 64; off <<= 1) {
        int y = __shfl_up(x, off);
        if (ln >= off) x += y;
    }
    if (ln == 63) wsum[wv] = x;
    __syncthreads();
    int base = 0;
    for (int w = 0; w < wv; w++) base += wsum[w];
    int excl = base + x - s;
    rowptr[b * (NUP + 1) + 2 * tid] = excl;
    rowptr[b * (NUP + 1) + 2 * tid + 1] = excl + d0;
    cursor[b * NUP + 2 * tid] = excl;
    cursor[b * NUP + 2 * tid + 1] = excl + d0;
    if (tid == 1023) rowptr[b * (NUP + 1) + NUP] = excl + s;
}

// CSR build: fill edge array (src = batch-local down node id).
__global__ void csr_fill(const int* __restrict__ mask, const int* __restrict__ knn,
                         const int* __restrict__ up_local, int* __restrict__ cursor,
                         int* __restrict__ edges) {
    int b = blockIdx.y;
    int i = blockIdx.x * 256 + threadIdx.x;
    int g = b * Nn + i;
    if (mask[g]) return;
    #pragma unroll
    for (int m = 0; m < MM; m++) {
        int un = knn[g * MM + m];
        int slot = atomicAdd(&cursor[b * NUP + up_local[b * Nn + un]], 1);
        edges[b * EPB + slot] = i;
    }
}

// Kernel D: gather-max. One wave per up node; lanes own 4 cols (float4).
__global__ void gather_kernel(const float4* __restrict__ upc, const int* __restrict__ rowptr,
                              const int* __restrict__ edges, float* __restrict__ out) {
    int b = blockIdx.y;
    int u = blockIdx.x * 4 + (threadIdx.x >> 6);
    int lane = threadIdx.x & 63;
    int node = __float_as_int(upc[b * NUP + u].w);
    int start = rowptr[b * (NUP + 1) + u];
    int end   = rowptr[b * (NUP + 1) + u + 1];
    const int* eb = edges + b * EPB;
    size_t rowbase = (size_t)b * Nn * Hh + (size_t)(lane << 2);
    float4 a0 = make_float4(-3.4e38f, -3.4e38f, -3.4e38f, -3.4e38f);
    float4 a1 = a0;
    int e = start;
    for (; e + 2 <= end; e += 2) {
        int s0 = eb[e], s1 = eb[e + 1];
        float4 v0 = *(const float4*)(out + rowbase + (size_t)s0 * Hh);
        float4 v1 = *(const float4*)(out + rowbase + (size_t)s1 * Hh);
        a0.x = fmaxf(a0.x, v0.x); a0.y = fmaxf(a0.y, v0.y);
        a0.z = fmaxf(a0.z, v0.z); a0.w = fmaxf(a0.w, v0.w);
        a1.x = fmaxf(a1.x, v1.x); a1.y = fmaxf(a1.y, v1.y);
        a1.z = fmaxf(a1.z, v1.z); a1.w = fmaxf(a1.w, v1.w);
    }
    if (e < end) {
        int s0 = eb[e];
        float4 v0 = *(const float4*)(out + rowbase + (size_t)s0 * Hh);
        a0.x = fmaxf(a0.x, v0.x); a0.y = fmaxf(a0.y, v0.y);
        a0.z = fmaxf(a0.z, v0.z); a0.w = fmaxf(a0.w, v0.w);
    }
    float4 r;
    r.x = fmaxf(a0.x, a1.x); r.y = fmaxf(a0.y, a1.y);
    r.z = fmaxf(a0.z, a1.z); r.w = fmaxf(a0.w, a1.w);
    if (start == end) r = make_float4(0.f, 0.f, 0.f, 0.f);
    *(float4*)(out + rowbase + (size_t)node * Hh) = r;
}

// Kernel E: zero down rows, write mask tail.
__global__ void finalize_kernel(const int* __restrict__ mask, float* __restrict__ out) {
    int b = blockIdx.y;
    int node = blockIdx.x * 4 + (threadIdx.x >> 6);
    int g = b * Nn + node;
    int lane = threadIdx.x & 63;
    bool up = mask[g] != 0;
    if (!up)
        *(float4*)(out + (size_t)g * Hh + (lane << 2)) = make_float4(0.f, 0.f, 0.f, 0.f);
    if (lane == 0) out[(size_t)Bb * Nn * Hh + g] = up ? 1.0f : 0.0f;
}

extern "C" void kernel_launch(void* const* d_in, const int* in_sizes, int n_in,
                              void* d_out, int out_size, void* d_ws, size_t ws_size,
                              hipStream_t stream) {
    const float* h    = (const float*)d_in[0];
    const float* sl   = (const float*)d_in[1];
    const float* sc   = (const float*)d_in[2];
    const float* W    = (const float*)d_in[3];
    const float* bias = (const float*)d_in[4];

    char* ws = (char*)d_ws;
    int* mask = (int*)ws;                 ws += (size_t)Bb * Nn * sizeof(int);
    int* knn  = (int*)ws;                 ws += (size_t)Bb * Nn * MM * sizeof(int);
    float4* upc = (float4*)ws;            ws += (size_t)Bb * NUP * sizeof(float4);
    float4* dnc = (float4*)ws;            ws += (size_t)Bb * NDOWN * sizeof(float4);
    unsigned short* Wt = (unsigned short*)ws; ws += (size_t)Hh * KP * sizeof(unsigned short);
    int* up_local = (int*)ws;             ws += (size_t)Bb * Nn * sizeof(int);
    int* deg = (int*)ws;                  ws += (size_t)Bb * NUP * sizeof(int);
    int* cursor = (int*)ws;               ws += (size_t)Bb * NUP * sizeof(int);
    int* rowptr = (int*)ws;               ws += (size_t)Bb * (NUP + 1) * sizeof(int);
    int* edges = (int*)ws;                // B*EPB ints
    float* outf = (float*)d_out;

    dim3 blk(256);
    select_kernel<<<dim3(Bb), dim3(1024), 0, stream>>>(sc, sl, mask, upc, dnc,
                                                       up_local, deg);
    knn_brute<<<dim3(NDOWN / 64, Bb), dim3(512), 0, stream>>>(upc, dnc,
                                                              up_local, knn, deg);
    csr_scan<<<dim3(Bb), dim3(1024), 0, stream>>>(deg, rowptr, cursor);
    csr_fill<<<dim3(Nn / 256, Bb), blk, 0, stream>>>(mask, knn, up_local, cursor, edges);
    wt_kernel<<<dim3(Hh), blk, 0, stream>>>(W, bias, Wt);
    feat_mfma<<<dim3(Nn / 128, 2, Bb), blk, 0, stream>>>(h, sl, sc, Wt, outf);
    gather_kernel<<<dim3(NUP / 4, Bb), blk, 0, stream>>>(upc, rowptr, edges, outf);
    finalize_kernel<<<dim3(Nn / 4, Bb), blk, 0, stream>>>(mask, outf);
}

// Round 6
// 278.933 us; speedup vs baseline: 1.2550x; 1.0785x over previous
//
#include <hip/hip_runtime.h>

#define Bb 8
#define Nn 8192
#define Hh 256
#define NUP 2048
#define NDOWN (Nn - NUP)
#define MM 5
#define EPB (NDOWN * MM)   // edges per batch = 30720
#define KP 288             // padded K for the feat GEMM (256 h + sl,score,1,pad)
#define LDA 36             // LDS row stride (bf16) for A/B tiles
#define LSTW 17            // hit-list stride (u64) per down

typedef short v8s __attribute__((ext_vector_type(8)));
typedef float v4f __attribute__((ext_vector_type(4)));

// fp32 -> bf16 round-to-nearest-even
__device__ __forceinline__ unsigned short bfc(float f) {
    unsigned u = __float_as_uint(f);
    return (unsigned short)((u + 0x7FFFu + ((u >> 16) & 1u)) >> 16);
}

// Find the bin (descending order) where the kth-largest element lands.
template <int NB>
__device__ void find_kth_bin(const int* hist, int kth, int tid,
                             int* wsumA, int* res, int* out_bin, int* out_cntgt) {
    constexpr int PER = NB / 1024;
    int ln = tid & 63, wv = tid >> 6;
    int b0 = NB - 1 - PER * tid;
    int c0 = hist[b0];
    int c1 = (PER == 2) ? hist[b0 - 1] : 0;
    int tot = c0 + c1;
    int x = tot;
    #pragma unroll
    for (int off = 1; off < 64; off <<= 1) {
        int y = __shfl_up(x, off);
        if (ln >= off) x += y;
    }
    if (ln == 63) wsumA[wv] = x;
    __syncthreads();
    int wbase = 0;
    for (int w = 0; w < wv; w++) wbase += wsumA[w];
    int excl = wbase + x - tot;
    if (excl < kth && excl + c0 >= kth) { res[0] = b0; res[1] = excl; }
    else if (PER == 2 && excl + c0 < kth && excl + c0 + c1 >= kth) { res[0] = b0 - 1; res[1] = excl + c0; }
    __syncthreads();
    *out_bin = res[0];
    *out_cntgt = res[1];
}

// Kernel A: exact top-NUP selection via 3-level radix select, fused compaction
// (ups -> upc, downs -> dnc, both in node order) + deg zeroing.
__global__ __launch_bounds__(1024) void select_kernel(
        const float* __restrict__ scores, const float* __restrict__ sl,
        int* __restrict__ mask, float4* __restrict__ upc,
        float4* __restrict__ dnc, int* __restrict__ deg) {
    int b = blockIdx.x;
    int tid = threadIdx.x;
    int ln = tid & 63, wv = tid >> 6;
    __shared__ int hist[2048];
    __shared__ int wsumA[16], wsumB[16];
    __shared__ int res[2];
    __shared__ int sbase[2];
    const float* s = scores + (size_t)b * Nn;

    deg[b * NUP + tid] = 0;
    deg[b * NUP + 1024 + tid] = 0;

    hist[tid] = 0; hist[tid + 1024] = 0;
    __syncthreads();
    for (int t = tid; t < Nn; t += 1024)
        atomicAdd(&hist[__float_as_uint(s[t]) >> 21], 1);
    __syncthreads();
    int B1, gt1;
    find_kth_bin<2048>(hist, NUP, tid, wsumA, res, &B1, &gt1);
    int slots1 = NUP - gt1;

    hist[tid] = 0; hist[tid + 1024] = 0;
    __syncthreads();
    for (int t = tid; t < Nn; t += 1024) {
        unsigned u = __float_as_uint(s[t]);
        if ((int)(u >> 21) == B1) atomicAdd(&hist[(u >> 10) & 0x7FF], 1);
    }
    __syncthreads();
    int B2, gt2;
    find_kth_bin<2048>(hist, slots1, tid, wsumA, res, &B2, &gt2);
    int slots2 = slots1 - gt2;
    unsigned hi22 = ((unsigned)B1 << 11) | (unsigned)B2;

    hist[tid] = 0; hist[tid + 1024] = 0;
    __syncthreads();
    for (int t = tid; t < Nn; t += 1024) {
        unsigned u = __float_as_uint(s[t]);
        if ((u >> 10) == hi22) atomicAdd(&hist[u & 0x3FF], 1);
    }
    __syncthreads();
    int B3, gt3;
    find_kth_bin<1024>(hist, slots2, tid, wsumA, res, &B3, &gt3);
    int slots_eq = slots2 - gt3;
    unsigned T = (hi22 << 10) | (unsigned)B3;

    if (tid == 0) { sbase[0] = 0; sbase[1] = 0; }
    __syncthreads();
    for (int t0 = 0; t0 < Nn; t0 += 1024) {
        int node = t0 + tid;
        int g = b * Nn + node;
        unsigned u = __float_as_uint(s[node]);
        bool eq = (u == T);
        unsigned long long bal = __ballot(eq);
        unsigned long long lmask = (1ull << ln) - 1ull;
        int pre = __popcll(bal & lmask);
        if (ln == 0) wsumA[wv] = __popcll(bal);
        __syncthreads();
        int eqbase = sbase[0];
        for (int w = 0; w < wv; w++) eqbase += wsumA[w];
        bool up = (u > T) || (eq && (eqbase + pre) < slots_eq);
        unsigned long long bal2 = __ballot(up);
        int pre2 = __popcll(bal2 & lmask);
        if (ln == 0) wsumB[wv] = __popcll(bal2);
        __syncthreads();
        int upbase = sbase[1];
        for (int w = 0; w < wv; w++) upbase += wsumB[w];
        float4 c;
        c.x = sl[(size_t)g * 3 + 0];
        c.y = sl[(size_t)g * 3 + 1];
        c.z = sl[(size_t)g * 3 + 2];
        c.w = __int_as_float(node);
        if (up) {
            upc[b * NUP + upbase + pre2] = c;
        } else {
            dnc[b * NDOWN + node - (upbase + pre2)] = c;
        }
        mask[g] = up ? 1 : 0;
        __syncthreads();
        if (tid == 0) {
            int se = 0, su = 0;
            for (int w = 0; w < 16; w++) { se += wsumA[w]; su += wsumB[w]; }
            sbase[0] += se; sbase[1] += su;
        }
        __syncthreads();
    }
}

// Kernel C: exact 5-NN, brute force, two-phase branchless. 512 threads =
// 64 downs (lanes) x 8 candidate slices (waves). Ups staged SoA (x/y/z, 24KB)
// -> 35KB LDS total -> 4 blocks/CU (32 waves, occupancy cap). Keys carry the
// LOCAL up index (upc is node-ordered, so local-idx tie-break == ref node-id
// tie-break) -> deg indexed directly, no up_local indirection anywhere.
// Phase 1: branchless top-5 d2 min/max network. Merge 8x5 -> exact global
// 5th distance thr. Phase 2: gate d2<=thr (hits = 5+ties, no overflow),
// append to short LDS list. Final: exact (d2,idx) sort. Phase-1/2 d2 are
// bit-identical; gate inclusive -> exact.
__global__ __launch_bounds__(512) void knn_brute(
        const float4* __restrict__ upc, const float4* __restrict__ dnc,
        int* __restrict__ knn, int* __restrict__ deg) {
    int b = blockIdx.y;
    int tid = threadIdx.x;
    int sub = tid >> 6, dn = tid & 63;   // 8 subs x 64 downs
    __shared__ float xs[NUP], ys[NUP], zs[NUP];       // 24 KB SoA
    __shared__ unsigned long long Ubuf[1312];          // 10.25 KB union
    __shared__ int lcnt[64];
    float* sF = (float*)Ubuf;                          // phase-1 partials + thr
    unsigned long long* lst = Ubuf + 32;               // hit lists (skips thr slots)

    float4 d = dnc[b * NDOWN + blockIdx.x * 64 + dn];
    float xd = d.x, yd = d.y, zd = d.z;
    int node = __float_as_int(d.w);

    const float4* U = upc + b * NUP;
    #pragma unroll
    for (int q = 0; q < 4; q++) {
        int i = q * 512 + tid;
        float4 u = U[i];
        xs[i] = u.x; ys[i] = u.y; zs[i] = u.z;
    }
    if (tid < 64) lcnt[tid] = 0;
    __syncthreads();

    // ---- phase 1: branchless top-5 distances over this thread's 256-slice
    float L[MM];
    #pragma unroll
    for (int m = 0; m < MM; m++) L[m] = 3.4e38f;
    const int j0 = sub * 256;
    #pragma unroll 4
    for (int j = j0; j < j0 + 256; ++j) {
        float dx = xs[j] - xd, dy = ys[j] - yd, dz = zs[j] - zd;
        float d2 = fmaf(dx, dx, fmaf(dy, dy, dz * dz));
        #pragma unroll
        for (int m = 0; m < MM; m++) {
            float lo = fminf(d2, L[m]), hi = fmaxf(d2, L[m]);
            L[m] = lo; d2 = hi;
        }
    }
    #pragma unroll
    for (int m = 0; m < MM; m++) sF[(sub * MM + m) * 64 + dn] = L[m];
    __syncthreads();

    // ---- merge to the true global 5th-smallest distance per down
    if (sub == 0) {
        float F[MM];
        #pragma unroll
        for (int m = 0; m < MM; m++) F[m] = 3.4e38f;
        for (int l = 0; l < 8; l++) {
            #pragma unroll
            for (int m = 0; m < MM; m++) {
                float v = sF[(l * MM + m) * 64 + dn];
                #pragma unroll
                for (int k = 0; k < MM; k++) {
                    float lo = fminf(v, F[k]), hi = fmaxf(v, F[k]);
                    F[k] = lo; v = hi;
                }
            }
        }
        sF[dn] = F[MM - 1];   // thr, in Ubuf[0..31] (below lst region)
    }
    __syncthreads();
    float thr = sF[dn];

    // ---- phase 2: tight-gated exact hit collection (local idx keys)
    #pragma unroll 4
    for (int j = j0; j < j0 + 256; ++j) {
        float dx = xs[j] - xd, dy = ys[j] - yd, dz = zs[j] - zd;
        float d2 = fmaf(dx, dx, fmaf(dy, dy, dz * dz));
        if (d2 <= thr) {
            unsigned long long key =
                ((unsigned long long)__float_as_uint(d2) << 32) |
                (unsigned long long)(unsigned)j;
            int s = atomicAdd(&lcnt[dn], 1);
            if (s < LSTW - 1) lst[dn * LSTW + s] = key;
        }
    }
    __syncthreads();

    // ---- final: exact (d2,idx) sort of the short list + outputs
    if (sub == 0) {
        unsigned long long fin[MM];
        #pragma unroll
        for (int m = 0; m < MM; m++) fin[m] = 0xFFFFFFFFFFFFFFFFull;
        int n = min(lcnt[dn], LSTW - 1);
        for (int s = 0; s < n; s++) {
            unsigned long long cand = lst[dn * LSTW + s];
            #pragma unroll
            for (int m = 0; m < MM; m++) {
                bool lt = cand < fin[m];
                unsigned long long lo = lt ? cand : fin[m];
                unsigned long long hi = lt ? fin[m] : cand;
                fin[m] = lo; cand = hi;
            }
        }
        int g = b * Nn + node;
        #pragma unroll
        for (int m = 0; m < MM; m++) {
            int lid = (int)(unsigned)(fin[m] & 0xFFFFFFFFull);
            knn[g * MM + m] = lid;                  // LOCAL up index
            atomicAdd(&deg[b * NUP + lid], 1);
        }
    }
}

// Kernel W: Wt[n][k] = bf16 of W-ext^T.
__global__ void wt_kernel(const float* __restrict__ W, const float* __restrict__ bias,
                          unsigned short* __restrict__ Wt) {
    int n = blockIdx.x;
    int k = threadIdx.x;
    Wt[n * KP + k] = bfc(W[(size_t)k * Hh + n]);
    if (k < KP - 256) {
        int kk = 256 + k;
        unsigned short v = 0;
        if (kk < 260)       v = bfc(W[(size_t)kk * Hh + n]);
        else if (kk == 260) v = bfc(bias[n]);
        Wt[n * KP + kk] = v;
    }
}

// Kernel B: feat GEMM via bf16 MFMA over DOWN rows only (up feats are never
// consumed: edges are down->up and gather overwrites up rows). 128 down-ranks
// x 128 cols per block; rows resolved via dnc node ids (ndid LDS).
__global__ void feat_mfma(const float* __restrict__ h, const float* __restrict__ sl,
                          const float* __restrict__ sc, const unsigned short* __restrict__ Wt,
                          const float4* __restrict__ dnc, float* __restrict__ out) {
    int b = blockIdx.z;
    int m0 = blockIdx.x * 128;   // down-rank tile base
    int n0 = blockIdx.y * 128;
    int tid = threadIdx.x;
    __shared__ unsigned short Al[128 * LDA];
    __shared__ unsigned short Bl[128 * LDA];
    __shared__ int ndid[128];
    int wid = tid >> 6, lane = tid & 63;
    int wm = (wid & 1) * 64, wn = (wid >> 1) * 64;
    int lm = lane & 15, quad = lane >> 4;
    if (tid < 128) ndid[tid] = __float_as_int(dnc[b * NDOWN + m0 + tid].w);
    v4f acc[4][4];
    #pragma unroll
    for (int i = 0; i < 4; i++)
        #pragma unroll
        for (int j = 0; j < 4; j++)
            acc[i][j] = (v4f){0.f, 0.f, 0.f, 0.f};
    const float* hb = h + (size_t)b * Nn * Hh;
    for (int t = 0; t < 9; t++) {
        int k0 = t * 32;
        __syncthreads();
        if (t < 8) {
            #pragma unroll
            for (int q = 0; q < 4; q++) {
                int e = q * 256 + tid;
                int row = e >> 3, kq = e & 7;
                float4 v = *(const float4*)(hb + (size_t)ndid[row] * Hh + k0 + kq * 4);
                ushort4 o = make_ushort4(bfc(v.x), bfc(v.y), bfc(v.z), bfc(v.w));
                *(ushort4*)(Al + row * LDA + kq * 4) = o;
            }
        } else if (tid < 128) {
            int row = tid;
            int g = b * Nn + ndid[row];
            unsigned short r[32];
            #pragma unroll
            for (int k = 0; k < 32; k++) r[k] = 0;
            r[0] = bfc(sl[(size_t)g * 3 + 0]);
            r[1] = bfc(sl[(size_t)g * 3 + 1]);
            r[2] = bfc(sl[(size_t)g * 3 + 2]);
            r[3] = bfc(sc[g]);
            r[4] = 0x3F80;  // 1.0 (bias column)
            #pragma unroll
            for (int q = 0; q < 8; q++)
                *(ushort4*)(Al + row * LDA + q * 4) =
                    make_ushort4(r[q * 4], r[q * 4 + 1], r[q * 4 + 2], r[q * 4 + 3]);
        }
        #pragma unroll
        for (int q = 0; q < 4; q++) {
            int e = q * 256 + tid;
            int n = e >> 3, kq = e & 7;
            ushort4 v = *(const ushort4*)(Wt + (size_t)(n0 + n) * KP + k0 + kq * 4);
            *(ushort4*)(Bl + n * LDA + kq * 4) = v;
        }
        __syncthreads();
        v8s af[4], bfr[4];
        #pragma unroll
        for (int i = 0; i < 4; i++)
            af[i] = *(const v8s*)(Al + (wm + i * 16 + lm) * LDA + quad * 8);
        #pragma unroll
        for (int j = 0; j < 4; j++)
            bfr[j] = *(const v8s*)(Bl + (wn + j * 16 + lm) * LDA + quad * 8);
        #pragma unroll
        for (int i = 0; i < 4; i++)
            #pragma unroll
            for (int j = 0; j < 4; j++)
                acc[i][j] = __builtin_amdgcn_mfma_f32_16x16x32_bf16(af[i], bfr[j], acc[i][j], 0, 0, 0);
    }
    #pragma unroll
    for (int i = 0; i < 4; i++) {
        #pragma unroll
        for (int r = 0; r < 4; r++) {
            int lrow = wm + i * 16 + quad * 4 + r;
            size_t base = ((size_t)b * Nn + ndid[lrow]) * Hh + n0 + wn + lm;
            #pragma unroll
            for (int j = 0; j < 4; j++)
                out[base + j * 16] = acc[i][j][r];
        }
    }
}

// CSR build: per-batch exclusive scan of deg -> rowptr (+ cursor copy).
__global__ __launch_bounds__(1024) void csr_scan(const int* __restrict__ deg,
                                                 int* __restrict__ rowptr,
                                                 int* __restrict__ cursor) {
    int b = blockIdx.x;
    int tid = threadIdx.x;
    int ln = tid & 63, wv = tid >> 6;
    __shared__ int wsum[16];
    int d0 = deg[b * NUP + 2 * tid], d1 = deg[b * NUP + 2 * tid + 1];
    int s = d0 + d1;
    int x = s;
    #pragma unroll
    for (int off = 1; off < 64; off <<= 1) {
        int y = __shfl_up(x, off);
        if (ln >= off) x += y;
    }
    if (ln == 63) wsum[wv] = x;
    __syncthreads();
    int base = 0;
    for (int w = 0; w < wv; w++) base += wsum[w];
    int excl = base + x - s;
    rowptr[b * (NUP + 1) + 2 * tid] = excl;
    rowptr[b * (NUP + 1) + 2 * tid + 1] = excl + d0;
    cursor[b * NUP + 2 * tid] = excl;
    cursor[b * NUP + 2 * tid + 1] = excl + d0;
    if (tid == 1023) rowptr[b * (NUP + 1) + NUP] = excl + s;
}

// CSR build: fill edge array (src = down node id; dst slot via local up idx).
__global__ void csr_fill(const int* __restrict__ mask, const int* __restrict__ knn,
                         int* __restrict__ cursor, int* __restrict__ edges) {
    int b = blockIdx.y;
    int i = blockIdx.x * 256 + threadIdx.x;
    int g = b * Nn + i;
    if (mask[g]) return;
    #pragma unroll
    for (int m = 0; m < MM; m++) {
        int un = knn[g * MM + m];   // local up index
        int slot = atomicAdd(&cursor[b * NUP + un], 1);
        edges[b * EPB + slot] = i;
    }
}

// Kernel D: gather-max. One wave per up node; lanes own 4 cols (float4).
// 4 accumulators -> 4 outstanding row loads per lane (latency hiding).
__global__ void gather_kernel(const float4* __restrict__ upc, const int* __restrict__ rowptr,
                              const int* __restrict__ edges, float* __restrict__ out) {
    int b = blockIdx.y;
    int u = blockIdx.x * 4 + (threadIdx.x >> 6);
    int lane = threadIdx.x & 63;
    int node = __float_as_int(upc[b * NUP + u].w);
    int start = rowptr[b * (NUP + 1) + u];
    int end   = rowptr[b * (NUP + 1) + u + 1];
    const int* eb = edges + b * EPB;
    size_t rowbase = (size_t)b * Nn * Hh + (size_t)(lane << 2);
    float4 a0 = make_float4(-3.4e38f, -3.4e38f, -3.4e38f, -3.4e38f);
    float4 a1 = a0, a2 = a0, a3 = a0;
    int e = start;
    for (; e + 4 <= end; e += 4) {
        int s0 = eb[e], s1 = eb[e + 1], s2 = eb[e + 2], s3 = eb[e + 3];
        float4 v0 = *(const float4*)(out + rowbase + (size_t)s0 * Hh);
        float4 v1 = *(const float4*)(out + rowbase + (size_t)s1 * Hh);
        float4 v2 = *(const float4*)(out + rowbase + (size_t)s2 * Hh);
        float4 v3 = *(const float4*)(out + rowbase + (size_t)s3 * Hh);
        a0.x = fmaxf(a0.x, v0.x); a0.y = fmaxf(a0.y, v0.y);
        a0.z = fmaxf(a0.z, v0.z); a0.w = fmaxf(a0.w, v0.w);
        a1.x = fmaxf(a1.x, v1.x); a1.y = fmaxf(a1.y, v1.y);
        a1.z = fmaxf(a1.z, v1.z); a1.w = fmaxf(a1.w, v1.w);
        a2.x = fmaxf(a2.x, v2.x); a2.y = fmaxf(a2.y, v2.y);
        a2.z = fmaxf(a2.z, v2.z); a2.w = fmaxf(a2.w, v2.w);
        a3.x = fmaxf(a3.x, v3.x); a3.y = fmaxf(a3.y, v3.y);
        a3.z = fmaxf(a3.z, v3.z); a3.w = fmaxf(a3.w, v3.w);
    }
    for (; e < end; e++) {
        int s0 = eb[e];
        float4 v0 = *(const float4*)(out + rowbase + (size_t)s0 * Hh);
        a0.x = fmaxf(a0.x, v0.x); a0.y = fmaxf(a0.y, v0.y);
        a0.z = fmaxf(a0.z, v0.z); a0.w = fmaxf(a0.w, v0.w);
    }
    float4 r;
    r.x = fmaxf(fmaxf(a0.x, a1.x), fmaxf(a2.x, a3.x));
    r.y = fmaxf(fmaxf(a0.y, a1.y), fmaxf(a2.y, a3.y));
    r.z = fmaxf(fmaxf(a0.z, a1.z), fmaxf(a2.z, a3.z));
    r.w = fmaxf(fmaxf(a0.w, a1.w), fmaxf(a2.w, a3.w));
    if (start == end) r = make_float4(0.f, 0.f, 0.f, 0.f);
    *(float4*)(out + rowbase + (size_t)node * Hh) = r;
}

// Kernel E: zero down rows, write mask tail.
__global__ void finalize_kernel(const int* __restrict__ mask, float* __restrict__ out) {
    int b = blockIdx.y;
    int node = blockIdx.x * 4 + (threadIdx.x >> 6);
    int g = b * Nn + node;
    int lane = threadIdx.x & 63;
    bool up = mask[g] != 0;
    if (!up)
        *(float4*)(out + (size_t)g * Hh + (lane << 2)) = make_float4(0.f, 0.f, 0.f, 0.f);
    if (lane == 0) out[(size_t)Bb * Nn * Hh + g] = up ? 1.0f : 0.0f;
}

extern "C" void kernel_launch(void* const* d_in, const int* in_sizes, int n_in,
                              void* d_out, int out_size, void* d_ws, size_t ws_size,
                              hipStream_t stream) {
    const float* h    = (const float*)d_in[0];
    const float* sl   = (const float*)d_in[1];
    const float* sc   = (const float*)d_in[2];
    const float* W    = (const float*)d_in[3];
    const float* bias = (const float*)d_in[4];

    char* ws = (char*)d_ws;
    int* mask = (int*)ws;                 ws += (size_t)Bb * Nn * sizeof(int);
    int* knn  = (int*)ws;                 ws += (size_t)Bb * Nn * MM * sizeof(int);
    float4* upc = (float4*)ws;            ws += (size_t)Bb * NUP * sizeof(float4);
    float4* dnc = (float4*)ws;            ws += (size_t)Bb * NDOWN * sizeof(float4);
    unsigned short* Wt = (unsigned short*)ws; ws += (size_t)Hh * KP * sizeof(unsigned short);
    int* deg = (int*)ws;                  ws += (size_t)Bb * NUP * sizeof(int);
    int* cursor = (int*)ws;               ws += (size_t)Bb * NUP * sizeof(int);
    int* rowptr = (int*)ws;               ws += (size_t)Bb * (NUP + 1) * sizeof(int);
    int* edges = (int*)ws;                // B*EPB ints
    float* outf = (float*)d_out;

    dim3 blk(256);
    select_kernel<<<dim3(Bb), dim3(1024), 0, stream>>>(sc, sl, mask, upc, dnc, deg);
    knn_brute<<<dim3(NDOWN / 64, Bb), dim3(512), 0, stream>>>(upc, dnc, knn, deg);
    csr_scan<<<dim3(Bb), dim3(1024), 0, stream>>>(deg, rowptr, cursor);
    csr_fill<<<dim3(Nn / 256, Bb), blk, 0, stream>>>(mask, knn, cursor, edges);
    wt_kernel<<<dim3(Hh), blk, 0, stream>>>(W, bias, Wt);
    feat_mfma<<<dim3(NDOWN / 128, 2, Bb), blk, 0, stream>>>(h, sl, sc, Wt, dnc, outf);
    gather_kernel<<<dim3(NUP / 4, Bb), blk, 0, stream>>>(upc, rowptr, edges, outf);
    finalize_kernel<<<dim3(Nn / 4, Bb), blk, 0, stream>>>(mask, outf);
}

// Round 7
// 264.545 us; speedup vs baseline: 1.3233x; 1.0544x over previous
//
#include <hip/hip_runtime.h>

#define Bb 8
#define Nn 8192
#define Hh 256
#define NUP 2048
#define NDOWN (Nn - NUP)
#define MM 5
#define EPB (NDOWN * MM)   // edges per batch = 30720
#define KP 288             // padded K for the feat GEMM (256 h + sl,score,1,pad)
#define LDA 36             // LDS row stride (bf16) for A/B tiles
#define LSTW 17            // hit-list stride (u64) per down

typedef short v8s __attribute__((ext_vector_type(8)));
typedef float v4f __attribute__((ext_vector_type(4)));

// fp32 -> bf16 round-to-nearest-even
__device__ __forceinline__ unsigned short bfc(float f) {
    unsigned u = __float_as_uint(f);
    return (unsigned short)((u + 0x7FFFu + ((u >> 16) & 1u)) >> 16);
}

// Find the bin (descending order) where the kth-largest element lands.
template <int NB>
__device__ void find_kth_bin(const int* hist, int kth, int tid,
                             int* wsumA, int* res, int* out_bin, int* out_cntgt) {
    constexpr int PER = NB / 1024;
    int ln = tid & 63, wv = tid >> 6;
    int b0 = NB - 1 - PER * tid;
    int c0 = hist[b0];
    int c1 = (PER == 2) ? hist[b0 - 1] : 0;
    int tot = c0 + c1;
    int x = tot;
    #pragma unroll
    for (int off = 1; off < 64; off <<= 1) {
        int y = __shfl_up(x, off);
        if (ln >= off) x += y;
    }
    if (ln == 63) wsumA[wv] = x;
    __syncthreads();
    int wbase = 0;
    for (int w = 0; w < wv; w++) wbase += wsumA[w];
    int excl = wbase + x - tot;
    if (excl < kth && excl + c0 >= kth) { res[0] = b0; res[1] = excl; }
    else if (PER == 2 && excl + c0 < kth && excl + c0 + c1 >= kth) { res[0] = b0 - 1; res[1] = excl + c0; }
    __syncthreads();
    *out_bin = res[0];
    *out_cntgt = res[1];
}

// Kernel A: exact top-NUP selection via 3-level radix select. Scores cached in
// registers across all passes (one read instead of four). Single-pass stable
// compaction: each thread owns 8 consecutive nodes; two block scans (eq rank,
// up rank) replace the old 8-tile x 6-barrier loop.
__global__ __launch_bounds__(1024) void select_kernel(
        const float* __restrict__ scores, const float* __restrict__ sl,
        int* __restrict__ mask, float4* __restrict__ upc,
        float4* __restrict__ dnc, int* __restrict__ deg) {
    int b = blockIdx.x;
    int tid = threadIdx.x;
    int ln = tid & 63, wv = tid >> 6;
    __shared__ int hist[2048];
    __shared__ int wsumA[16];
    __shared__ int res[2];
    const float* s = scores + (size_t)b * Nn;

    deg[b * NUP + tid] = 0;
    deg[b * NUP + 1024 + tid] = 0;

    float4 sa = *(const float4*)(s + tid * 8);
    float4 sb = *(const float4*)(s + tid * 8 + 4);
    unsigned ub[8] = {__float_as_uint(sa.x), __float_as_uint(sa.y),
                      __float_as_uint(sa.z), __float_as_uint(sa.w),
                      __float_as_uint(sb.x), __float_as_uint(sb.y),
                      __float_as_uint(sb.z), __float_as_uint(sb.w)};

    hist[tid] = 0; hist[tid + 1024] = 0;
    __syncthreads();
    #pragma unroll
    for (int k = 0; k < 8; k++) atomicAdd(&hist[ub[k] >> 21], 1);
    __syncthreads();
    int B1, gt1;
    find_kth_bin<2048>(hist, NUP, tid, wsumA, res, &B1, &gt1);
    int slots1 = NUP - gt1;

    hist[tid] = 0; hist[tid + 1024] = 0;
    __syncthreads();
    #pragma unroll
    for (int k = 0; k < 8; k++)
        if ((int)(ub[k] >> 21) == B1) atomicAdd(&hist[(ub[k] >> 10) & 0x7FF], 1);
    __syncthreads();
    int B2, gt2;
    find_kth_bin<2048>(hist, slots1, tid, wsumA, res, &B2, &gt2);
    int slots2 = slots1 - gt2;
    unsigned hi22 = ((unsigned)B1 << 11) | (unsigned)B2;

    hist[tid] = 0; hist[tid + 1024] = 0;
    __syncthreads();
    #pragma unroll
    for (int k = 0; k < 8; k++)
        if ((ub[k] >> 10) == hi22) atomicAdd(&hist[ub[k] & 0x3FF], 1);
    __syncthreads();
    int B3, gt3;
    find_kth_bin<1024>(hist, slots2, tid, wsumA, res, &B3, &gt3);
    int slots_eq = slots2 - gt3;
    unsigned T = (hi22 << 10) | (unsigned)B3;

    // ---- single-pass stable compaction ----
    int eqc = 0;
    #pragma unroll
    for (int k = 0; k < 8; k++) eqc += (ub[k] == T) ? 1 : 0;
    int x = eqc;
    #pragma unroll
    for (int off = 1; off < 64; off <<= 1) {
        int y = __shfl_up(x, off);
        if (ln >= off) x += y;
    }
    if (ln == 63) wsumA[wv] = x;
    __syncthreads();
    int eqb = x - eqc;
    for (int w = 0; w < wv; w++) eqb += wsumA[w];
    __syncthreads();   // wsumA reusable

    int upcnt = 0, eqrun = 0, upf = 0;
    #pragma unroll
    for (int k = 0; k < 8; k++) {
        bool eq = (ub[k] == T);
        bool up = (ub[k] > T) || (eq && (eqb + eqrun) < slots_eq);
        eqrun += eq ? 1 : 0;
        upf |= (up ? 1 : 0) << k;
        upcnt += up ? 1 : 0;
    }
    x = upcnt;
    #pragma unroll
    for (int off = 1; off < 64; off <<= 1) {
        int y = __shfl_up(x, off);
        if (ln >= off) x += y;
    }
    if (ln == 63) wsumA[wv] = x;
    __syncthreads();
    int upb = x - upcnt;
    for (int w = 0; w < wv; w++) upb += wsumA[w];

    int uprun = 0;
    #pragma unroll
    for (int k = 0; k < 8; k++) {
        int node = tid * 8 + k;
        int g = b * Nn + node;
        float4 c;
        c.x = sl[(size_t)g * 3 + 0];
        c.y = sl[(size_t)g * 3 + 1];
        c.z = sl[(size_t)g * 3 + 2];
        c.w = __int_as_float(node);
        bool up = (upf >> k) & 1;
        if (up) upc[b * NUP + upb + uprun] = c;
        else    dnc[b * NDOWN + node - (upb + uprun)] = c;
        mask[g] = up ? 1 : 0;
        uprun += up ? 1 : 0;
    }
}

// Kernel C: exact 5-NN, brute force, two-phase branchless. 512 threads =
// 64 downs (lanes) x 8 candidate slices (waves); ups staged SoA in LDS.
// Phase 1: branchless top-5 d2 via v_med3_f32 insert (5 VALU vs 10 for the
// min/max network: for sorted L0<=..<=L4, insert v = med3 chain descending +
// min at the bottom). Merge 8x5 -> exact global 5th distance thr. Phase 2:
// gate d2<=thr, append (d2,local-idx) u64 keys to short LDS list. Final:
// exact (d2,idx) sort = ref tie-breaking (upc node-ordered).
__global__ __launch_bounds__(512) void knn_brute(
        const float4* __restrict__ upc, const float4* __restrict__ dnc,
        int* __restrict__ knn, int* __restrict__ deg) {
    int b = blockIdx.y;
    int tid = threadIdx.x;
    int sub = tid >> 6, dn = tid & 63;   // 8 subs x 64 downs
    __shared__ float xs[NUP], ys[NUP], zs[NUP];       // 24 KB SoA
    __shared__ unsigned long long Ubuf[1312];          // 10.25 KB union
    __shared__ int lcnt[64];
    float* sF = (float*)Ubuf;                          // phase-1 partials + thr
    unsigned long long* lst = Ubuf + 32;               // hit lists (above thr slots)

    float4 d = dnc[b * NDOWN + blockIdx.x * 64 + dn];
    float xd = d.x, yd = d.y, zd = d.z;
    int node = __float_as_int(d.w);

    const float4* U = upc + b * NUP;
    #pragma unroll
    for (int q = 0; q < 4; q++) {
        int i = q * 512 + tid;
        float4 u = U[i];
        xs[i] = u.x; ys[i] = u.y; zs[i] = u.z;
    }
    if (tid < 64) lcnt[tid] = 0;
    __syncthreads();

    // ---- phase 1: branchless top-5 distances (med3 insert)
    float L0 = 3.4e38f, L1 = 3.4e38f, L2 = 3.4e38f, L3 = 3.4e38f, L4 = 3.4e38f;
    const int j0 = sub * 256;
    #pragma unroll 4
    for (int j = j0; j < j0 + 256; ++j) {
        float dx = xs[j] - xd, dy = ys[j] - yd, dz = zs[j] - zd;
        float d2 = fmaf(dx, dx, fmaf(dy, dy, dz * dz));
        L4 = __builtin_amdgcn_fmed3f(d2, L3, L4);
        L3 = __builtin_amdgcn_fmed3f(d2, L2, L3);
        L2 = __builtin_amdgcn_fmed3f(d2, L1, L2);
        L1 = __builtin_amdgcn_fmed3f(d2, L0, L1);
        L0 = fminf(d2, L0);
    }
    sF[(sub * MM + 0) * 64 + dn] = L0;
    sF[(sub * MM + 1) * 64 + dn] = L1;
    sF[(sub * MM + 2) * 64 + dn] = L2;
    sF[(sub * MM + 3) * 64 + dn] = L3;
    sF[(sub * MM + 4) * 64 + dn] = L4;
    __syncthreads();

    // ---- merge to the true global 5th-smallest distance per down
    if (sub == 0) {
        float F0 = 3.4e38f, F1 = 3.4e38f, F2 = 3.4e38f, F3 = 3.4e38f, F4 = 3.4e38f;
        for (int l = 0; l < 8; l++) {
            #pragma unroll
            for (int m = 0; m < MM; m++) {
                float v = sF[(l * MM + m) * 64 + dn];
                F4 = __builtin_amdgcn_fmed3f(v, F3, F4);
                F3 = __builtin_amdgcn_fmed3f(v, F2, F3);
                F2 = __builtin_amdgcn_fmed3f(v, F1, F2);
                F1 = __builtin_amdgcn_fmed3f(v, F0, F1);
                F0 = fminf(v, F0);
            }
        }
        sF[dn] = F4;   // thr, in Ubuf[0..32) (below lst region)
    }
    __syncthreads();
    float thr = sF[dn];

    // ---- phase 2: tight-gated exact hit collection (local idx keys)
    #pragma unroll 4
    for (int j = j0; j < j0 + 256; ++j) {
        float dx = xs[j] - xd, dy = ys[j] - yd, dz = zs[j] - zd;
        float d2 = fmaf(dx, dx, fmaf(dy, dy, dz * dz));
        if (d2 <= thr) {
            unsigned long long key =
                ((unsigned long long)__float_as_uint(d2) << 32) |
                (unsigned long long)(unsigned)j;
            int s = atomicAdd(&lcnt[dn], 1);
            if (s < LSTW - 1) lst[dn * LSTW + s] = key;
        }
    }
    __syncthreads();

    // ---- final: exact (d2,idx) sort of the short list + outputs
    if (sub == 0) {
        unsigned long long fin[MM];
        #pragma unroll
        for (int m = 0; m < MM; m++) fin[m] = 0xFFFFFFFFFFFFFFFFull;
        int n = min(lcnt[dn], LSTW - 1);
        for (int s = 0; s < n; s++) {
            unsigned long long cand = lst[dn * LSTW + s];
            #pragma unroll
            for (int m = 0; m < MM; m++) {
                bool lt = cand < fin[m];
                unsigned long long lo = lt ? cand : fin[m];
                unsigned long long hi = lt ? fin[m] : cand;
                fin[m] = lo; cand = hi;
            }
        }
        int g = b * Nn + node;
        #pragma unroll
        for (int m = 0; m < MM; m++) {
            int lid = (int)(unsigned)(fin[m] & 0xFFFFFFFFull);
            knn[g * MM + m] = lid;                  // LOCAL up index
            atomicAdd(&deg[b * NUP + lid], 1);
        }
    }
}

// Kernel W: Wt[n][k] = bf16 of W-ext^T.
__global__ void wt_kernel(const float* __restrict__ W, const float* __restrict__ bias,
                          unsigned short* __restrict__ Wt) {
    int n = blockIdx.x;
    int k = threadIdx.x;
    Wt[n * KP + k] = bfc(W[(size_t)k * Hh + n]);
    if (k < KP - 256) {
        int kk = 256 + k;
        unsigned short v = 0;
        if (kk < 260)       v = bfc(W[(size_t)kk * Hh + n]);
        else if (kk == 260) v = bfc(bias[n]);
        Wt[n * KP + kk] = v;
    }
}

// Kernel B: feat GEMM via bf16 MFMA over DOWN rows only (up feats are never
// consumed: edges are down->up and gather overwrites up rows). 128 down-ranks
// x 128 cols per block; rows resolved via dnc node ids (ndid LDS).
__global__ void feat_mfma(const float* __restrict__ h, const float* __restrict__ sl,
                          const float* __restrict__ sc, const unsigned short* __restrict__ Wt,
                          const float4* __restrict__ dnc, float* __restrict__ out) {
    int b = blockIdx.z;
    int m0 = blockIdx.x * 128;   // down-rank tile base
    int n0 = blockIdx.y * 128;
    int tid = threadIdx.x;
    __shared__ unsigned short Al[128 * LDA];
    __shared__ unsigned short Bl[128 * LDA];
    __shared__ int ndid[128];
    int wid = tid >> 6, lane = tid & 63;
    int wm = (wid & 1) * 64, wn = (wid >> 1) * 64;
    int lm = lane & 15, quad = lane >> 4;
    if (tid < 128) ndid[tid] = __float_as_int(dnc[b * NDOWN + m0 + tid].w);
    v4f acc[4][4];
    #pragma unroll
    for (int i = 0; i < 4; i++)
        #pragma unroll
        for (int j = 0; j < 4; j++)
            acc[i][j] = (v4f){0.f, 0.f, 0.f, 0.f};
    const float* hb = h + (size_t)b * Nn * Hh;
    for (int t = 0; t < 9; t++) {
        int k0 = t * 32;
        __syncthreads();
        if (t < 8) {
            #pragma unroll
            for (int q = 0; q < 4; q++) {
                int e = q * 256 + tid;
                int row = e >> 3, kq = e & 7;
                float4 v = *(const float4*)(hb + (size_t)ndid[row] * Hh + k0 + kq * 4);
                ushort4 o = make_ushort4(bfc(v.x), bfc(v.y), bfc(v.z), bfc(v.w));
                *(ushort4*)(Al + row * LDA + kq * 4) = o;
            }
        } else if (tid < 128) {
            int row = tid;
            int g = b * Nn + ndid[row];
            unsigned short r[32];
            #pragma unroll
            for (int k = 0; k < 32; k++) r[k] = 0;
            r[0] = bfc(sl[(size_t)g * 3 + 0]);
            r[1] = bfc(sl[(size_t)g * 3 + 1]);
            r[2] = bfc(sl[(size_t)g * 3 + 2]);
            r[3] = bfc(sc[g]);
            r[4] = 0x3F80;  // 1.0 (bias column)
            #pragma unroll
            for (int q = 0; q < 8; q++)
                *(ushort4*)(Al + row * LDA + q * 4) =
                    make_ushort4(r[q * 4], r[q * 4 + 1], r[q * 4 + 2], r[q * 4 + 3]);
        }
        #pragma unroll
        for (int q = 0; q < 4; q++) {
            int e = q * 256 + tid;
            int n = e >> 3, kq = e & 7;
            ushort4 v = *(const ushort4*)(Wt + (size_t)(n0 + n) * KP + k0 + kq * 4);
            *(ushort4*)(Bl + n * LDA + kq * 4) = v;
        }
        __syncthreads();
        v8s af[4], bfr[4];
        #pragma unroll
        for (int i = 0; i < 4; i++)
            af[i] = *(const v8s*)(Al + (wm + i * 16 + lm) * LDA + quad * 8);
        #pragma unroll
        for (int j = 0; j < 4; j++)
            bfr[j] = *(const v8s*)(Bl + (wn + j * 16 + lm) * LDA + quad * 8);
        #pragma unroll
        for (int i = 0; i < 4; i++)
            #pragma unroll
            for (int j = 0; j < 4; j++)
                acc[i][j] = __builtin_amdgcn_mfma_f32_16x16x32_bf16(af[i], bfr[j], acc[i][j], 0, 0, 0);
    }
    #pragma unroll
    for (int i = 0; i < 4; i++) {
        #pragma unroll
        for (int r = 0; r < 4; r++) {
            int lrow = wm + i * 16 + quad * 4 + r;
            size_t base = ((size_t)b * Nn + ndid[lrow]) * Hh + n0 + wn + lm;
            #pragma unroll
            for (int j = 0; j < 4; j++)
                out[base + j * 16] = acc[i][j][r];
        }
    }
}

// CSR build: per-batch exclusive scan of deg -> rowptr (+ cursor copy).
__global__ __launch_bounds__(1024) void csr_scan(const int* __restrict__ deg,
                                                 int* __restrict__ rowptr,
                                                 int* __restrict__ cursor) {
    int b = blockIdx.x;
    int tid = threadIdx.x;
    int ln = tid & 63, wv = tid >> 6;
    __shared__ int wsum[16];
    int d0 = deg[b * NUP + 2 * tid], d1 = deg[b * NUP + 2 * tid + 1];
    int s = d0 + d1;
    int x = s;
    #pragma unroll
    for (int off = 1; off < 64; off <<= 1) {
        int y = __shfl_up(x, off);
        if (ln >= off) x += y;
    }
    if (ln == 63) wsum[wv] = x;
    __syncthreads();
    int base = 0;
    for (int w = 0; w < wv; w++) base += wsum[w];
    int excl = base + x - s;
    rowptr[b * (NUP + 1) + 2 * tid] = excl;
    rowptr[b * (NUP + 1) + 2 * tid + 1] = excl + d0;
    cursor[b * NUP + 2 * tid] = excl;
    cursor[b * NUP + 2 * tid + 1] = excl + d0;
    if (tid == 1023) rowptr[b * (NUP + 1) + NUP] = excl + s;
}

// CSR build: fill edge array (src = down node id; dst slot via local up idx).
// Iterates down ranks via dnc directly -- no mask reads, no idle threads.
__global__ void csr_fill(const float4* __restrict__ dnc, const int* __restrict__ knn,
                         int* __restrict__ cursor, int* __restrict__ edges) {
    int b = blockIdx.y;
    int r = blockIdx.x * 256 + threadIdx.x;
    int node = __float_as_int(dnc[b * NDOWN + r].w);
    int g = b * Nn + node;
    #pragma unroll
    for (int m = 0; m < MM; m++) {
        int un = knn[g * MM + m];   // local up index
        int slot = atomicAdd(&cursor[b * NUP + un], 1);
        edges[b * EPB + slot] = node;
    }
}

// Kernel D: gather-max. One wave per up node; lanes own 4 cols (float4).
// 4 accumulators -> 4 outstanding row loads per lane (latency hiding).
__global__ void gather_kernel(const float4* __restrict__ upc, const int* __restrict__ rowptr,
                              const int* __restrict__ edges, float* __restrict__ out) {
    int b = blockIdx.y;
    int u = blockIdx.x * 4 + (threadIdx.x >> 6);
    int lane = threadIdx.x & 63;
    int node = __float_as_int(upc[b * NUP + u].w);
    int start = rowptr[b * (NUP + 1) + u];
    int end   = rowptr[b * (NUP + 1) + u + 1];
    const int* eb = edges + b * EPB;
    size_t rowbase = (size_t)b * Nn * Hh + (size_t)(lane << 2);
    float4 a0 = make_float4(-3.4e38f, -3.4e38f, -3.4e38f, -3.4e38f);
    float4 a1 = a0, a2 = a0, a3 = a0;
    int e = start;
    for (; e + 4 <= end; e += 4) {
        int s0 = eb[e], s1 = eb[e + 1], s2 = eb[e + 2], s3 = eb[e + 3];
        float4 v0 = *(const float4*)(out + rowbase + (size_t)s0 * Hh);
        float4 v1 = *(const float4*)(out + rowbase + (size_t)s1 * Hh);
        float4 v2 = *(const float4*)(out + rowbase + (size_t)s2 * Hh);
        float4 v3 = *(const float4*)(out + rowbase + (size_t)s3 * Hh);
        a0.x = fmaxf(a0.x, v0.x); a0.y = fmaxf(a0.y, v0.y);
        a0.z = fmaxf(a0.z, v0.z); a0.w = fmaxf(a0.w, v0.w);
        a1.x = fmaxf(a1.x, v1.x); a1.y = fmaxf(a1.y, v1.y);
        a1.z = fmaxf(a1.z, v1.z); a1.w = fmaxf(a1.w, v1.w);
        a2.x = fmaxf(a2.x, v2.x); a2.y = fmaxf(a2.y, v2.y);
        a2.z = fmaxf(a2.z, v2.z); a2.w = fmaxf(a2.w, v2.w);
        a3.x = fmaxf(a3.x, v3.x); a3.y = fmaxf(a3.y, v3.y);
        a3.z = fmaxf(a3.z, v3.z); a3.w = fmaxf(a3.w, v3.w);
    }
    for (; e < end; e++) {
        int s0 = eb[e];
        float4 v0 = *(const float4*)(out + rowbase + (size_t)s0 * Hh);
        a0.x = fmaxf(a0.x, v0.x); a0.y = fmaxf(a0.y, v0.y);
        a0.z = fmaxf(a0.z, v0.z); a0.w = fmaxf(a0.w, v0.w);
    }
    float4 r;
    r.x = fmaxf(fmaxf(a0.x, a1.x), fmaxf(a2.x, a3.x));
    r.y = fmaxf(fmaxf(a0.y, a1.y), fmaxf(a2.y, a3.y));
    r.z = fmaxf(fmaxf(a0.z, a1.z), fmaxf(a2.z, a3.z));
    r.w = fmaxf(fmaxf(a0.w, a1.w), fmaxf(a2.w, a3.w));
    if (start == end) r = make_float4(0.f, 0.f, 0.f, 0.f);
    *(float4*)(out + rowbase + (size_t)node * Hh) = r;
}

// Kernel E: zero down rows, write mask tail.
__global__ void finalize_kernel(const int* __restrict__ mask, float* __restrict__ out) {
    int b = blockIdx.y;
    int node = blockIdx.x * 4 + (threadIdx.x >> 6);
    int g = b * Nn + node;
    int lane = threadIdx.x & 63;
    bool up = mask[g] != 0;
    if (!up)
        *(float4*)(out + (size_t)g * Hh + (lane << 2)) = make_float4(0.f, 0.f, 0.f, 0.f);
    if (lane == 0) out[(size_t)Bb * Nn * Hh + g] = up ? 1.0f : 0.0f;
}

extern "C" void kernel_launch(void* const* d_in, const int* in_sizes, int n_in,
                              void* d_out, int out_size, void* d_ws, size_t ws_size,
                              hipStream_t stream) {
    const float* h    = (const float*)d_in[0];
    const float* sl   = (const float*)d_in[1];
    const float* sc   = (const float*)d_in[2];
    const float* W    = (const float*)d_in[3];
    const float* bias = (const float*)d_in[4];

    char* ws = (char*)d_ws;
    int* mask = (int*)ws;                 ws += (size_t)Bb * Nn * sizeof(int);
    int* knn  = (int*)ws;                 ws += (size_t)Bb * Nn * MM * sizeof(int);
    float4* upc = (float4*)ws;            ws += (size_t)Bb * NUP * sizeof(float4);
    float4* dnc = (float4*)ws;            ws += (size_t)Bb * NDOWN * sizeof(float4);
    unsigned short* Wt = (unsigned short*)ws; ws += (size_t)Hh * KP * sizeof(unsigned short);
    int* deg = (int*)ws;                  ws += (size_t)Bb * NUP * sizeof(int);
    int* cursor = (int*)ws;               ws += (size_t)Bb * NUP * sizeof(int);
    int* rowptr = (int*)ws;               ws += (size_t)Bb * (NUP + 1) * sizeof(int);
    int* edges = (int*)ws;                // B*EPB ints
    float* outf = (float*)d_out;

    dim3 blk(256);
    select_kernel<<<dim3(Bb), dim3(1024), 0, stream>>>(sc, sl, mask, upc, dnc, deg);
    knn_brute<<<dim3(NDOWN / 64, Bb), dim3(512), 0, stream>>>(upc, dnc, knn, deg);
    csr_scan<<<dim3(Bb), dim3(1024), 0, stream>>>(deg, rowptr, cursor);
    csr_fill<<<dim3(NDOWN / 256, Bb), blk, 0, stream>>>(dnc, knn, cursor, edges);
    wt_kernel<<<dim3(Hh), blk, 0, stream>>>(W, bias, Wt);
    feat_mfma<<<dim3(NDOWN / 128, 2, Bb), blk, 0, stream>>>(h, sl, sc, Wt, dnc, outf);
    gather_kernel<<<dim3(NUP / 4, Bb), blk, 0, stream>>>(upc, rowptr, edges, outf);
    finalize_kernel<<<dim3(Nn / 4, Bb), blk, 0, stream>>>(mask, outf);
}

// Round 8
// 263.042 us; speedup vs baseline: 1.3309x; 1.0057x over previous
//
#include <hip/hip_runtime.h>

#define Bb 8
#define Nn 8192
#define Hh 256
#define NUP 2048
#define NDOWN (Nn - NUP)
#define MM 5
#define EPB (NDOWN * MM)   // edges per batch = 30720
#define KP 288             // padded K for the feat GEMM (256 h + sl,score,1,pad)
#define LDA 36             // LDS row stride (bf16) for A/B tiles
#define LSTW 20            // hit-list stride (u64) per down (19 usable)

typedef short v8s __attribute__((ext_vector_type(8)));
typedef float v4f __attribute__((ext_vector_type(4)));

// fp32 -> bf16 round-to-nearest-even
__device__ __forceinline__ unsigned short bfc(float f) {
    unsigned u = __float_as_uint(f);
    return (unsigned short)((u + 0x7FFFu + ((u >> 16) & 1u)) >> 16);
}

// Find the bin (descending order) where the kth-largest element lands.
template <int NB>
__device__ void find_kth_bin(const int* hist, int kth, int tid,
                             int* wsumA, int* res, int* out_bin, int* out_cntgt) {
    constexpr int PER = NB / 1024;
    int ln = tid & 63, wv = tid >> 6;
    int b0 = NB - 1 - PER * tid;
    int c0 = hist[b0];
    int c1 = (PER == 2) ? hist[b0 - 1] : 0;
    int tot = c0 + c1;
    int x = tot;
    #pragma unroll
    for (int off = 1; off < 64; off <<= 1) {
        int y = __shfl_up(x, off);
        if (ln >= off) x += y;
    }
    if (ln == 63) wsumA[wv] = x;
    __syncthreads();
    int wbase = 0;
    for (int w = 0; w < wv; w++) wbase += wsumA[w];
    int excl = wbase + x - tot;
    if (excl < kth && excl + c0 >= kth) { res[0] = b0; res[1] = excl; }
    else if (PER == 2 && excl + c0 < kth && excl + c0 + c1 >= kth) { res[0] = b0 - 1; res[1] = excl + c0; }
    __syncthreads();
    *out_bin = res[0];
    *out_cntgt = res[1];
}

// Kernel A: exact top-NUP selection via 3-level radix select. Scores cached in
// registers; single-pass stable compaction (two block scans); sl loaded as 6
// aligned float4 per thread (96B contiguous). No mask array -- the node
// partition lives entirely in upc/dnc.
__global__ __launch_bounds__(1024) void select_kernel(
        const float* __restrict__ scores, const float* __restrict__ sl,
        float4* __restrict__ upc, float4* __restrict__ dnc,
        int* __restrict__ deg) {
    int b = blockIdx.x;
    int tid = threadIdx.x;
    int ln = tid & 63, wv = tid >> 6;
    __shared__ int hist[2048];
    __shared__ int wsumA[16];
    __shared__ int res[2];
    const float* s = scores + (size_t)b * Nn;

    deg[b * NUP + tid] = 0;
    deg[b * NUP + 1024 + tid] = 0;

    float4 sa = *(const float4*)(s + tid * 8);
    float4 sb = *(const float4*)(s + tid * 8 + 4);
    unsigned ub[8] = {__float_as_uint(sa.x), __float_as_uint(sa.y),
                      __float_as_uint(sa.z), __float_as_uint(sa.w),
                      __float_as_uint(sb.x), __float_as_uint(sb.y),
                      __float_as_uint(sb.z), __float_as_uint(sb.w)};

    hist[tid] = 0; hist[tid + 1024] = 0;
    __syncthreads();
    #pragma unroll
    for (int k = 0; k < 8; k++) atomicAdd(&hist[ub[k] >> 21], 1);
    __syncthreads();
    int B1, gt1;
    find_kth_bin<2048>(hist, NUP, tid, wsumA, res, &B1, &gt1);
    int slots1 = NUP - gt1;

    hist[tid] = 0; hist[tid + 1024] = 0;
    __syncthreads();
    #pragma unroll
    for (int k = 0; k < 8; k++)
        if ((int)(ub[k] >> 21) == B1) atomicAdd(&hist[(ub[k] >> 10) & 0x7FF], 1);
    __syncthreads();
    int B2, gt2;
    find_kth_bin<2048>(hist, slots1, tid, wsumA, res, &B2, &gt2);
    int slots2 = slots1 - gt2;
    unsigned hi22 = ((unsigned)B1 << 11) | (unsigned)B2;

    hist[tid] = 0; hist[tid + 1024] = 0;
    __syncthreads();
    #pragma unroll
    for (int k = 0; k < 8; k++)
        if ((ub[k] >> 10) == hi22) atomicAdd(&hist[ub[k] & 0x3FF], 1);
    __syncthreads();
    int B3, gt3;
    find_kth_bin<1024>(hist, slots2, tid, wsumA, res, &B3, &gt3);
    int slots_eq = slots2 - gt3;
    unsigned T = (hi22 << 10) | (unsigned)B3;

    // ---- single-pass stable compaction ----
    int eqc = 0;
    #pragma unroll
    for (int k = 0; k < 8; k++) eqc += (ub[k] == T) ? 1 : 0;
    int x = eqc;
    #pragma unroll
    for (int off = 1; off < 64; off <<= 1) {
        int y = __shfl_up(x, off);
        if (ln >= off) x += y;
    }
    if (ln == 63) wsumA[wv] = x;
    __syncthreads();
    int eqb = x - eqc;
    for (int w = 0; w < wv; w++) eqb += wsumA[w];
    __syncthreads();   // wsumA reusable

    int upcnt = 0, eqrun = 0, upf = 0;
    #pragma unroll
    for (int k = 0; k < 8; k++) {
        bool eq = (ub[k] == T);
        bool up = (ub[k] > T) || (eq && (eqb + eqrun) < slots_eq);
        eqrun += eq ? 1 : 0;
        upf |= (up ? 1 : 0) << k;
        upcnt += up ? 1 : 0;
    }
    x = upcnt;
    #pragma unroll
    for (int off = 1; off < 64; off <<= 1) {
        int y = __shfl_up(x, off);
        if (ln >= off) x += y;
    }
    if (ln == 63) wsumA[wv] = x;
    __syncthreads();
    int upb = x - upcnt;
    for (int w = 0; w < wv; w++) upb += wsumA[w];

    // ---- vectorized sl read: 96 contiguous bytes per thread (16B-aligned)
    const float* slb = sl + ((size_t)b * Nn + (size_t)tid * 8) * 3;
    float fb[24];
    *(float4*)(fb + 0)  = *(const float4*)(slb + 0);
    *(float4*)(fb + 4)  = *(const float4*)(slb + 4);
    *(float4*)(fb + 8)  = *(const float4*)(slb + 8);
    *(float4*)(fb + 12) = *(const float4*)(slb + 12);
    *(float4*)(fb + 16) = *(const float4*)(slb + 16);
    *(float4*)(fb + 20) = *(const float4*)(slb + 20);

    int uprun = 0;
    #pragma unroll
    for (int k = 0; k < 8; k++) {
        int node = tid * 8 + k;
        float4 c;
        c.x = fb[3 * k]; c.y = fb[3 * k + 1]; c.z = fb[3 * k + 2];
        c.w = __int_as_float(node);
        bool up = (upf >> k) & 1;
        if (up) upc[b * NUP + upb + uprun] = c;
        else    dnc[b * NDOWN + node - (upb + uprun)] = c;
        uprun += up ? 1 : 0;
    }
}

// Kernel C: exact 5-NN, brute force, two-phase. 512 threads = 64 downs
// (lanes) x 8 candidate slices (waves). Ups staged AoS (x,y,z,|u|^2) -> one
// ds_read_b128 per candidate (was 3x b32). Phase 1 ranks by the expanded
// metric t = |u|^2 - 2 u.d (= d2 - |d|^2 in reals; 3 FMA) with med3 top-5.
// thr = T5_t + |d|^2 + 1e-3 is a guaranteed upper bound on the exact 5th
// distance (f32 cancellation error of the expansion is <= ~1e-4). Phase 2
// recomputes the BIT-IDENTICAL d2 of the previous kernel and gates d2<=thr
// inclusively -> superset hit list -> exact (d2,local idx) sort = identical
// output (upc node-ordered => local-idx tie-break == ref node-id tie-break).
__global__ __launch_bounds__(512) void knn_brute(
        const float4* __restrict__ upc, const float4* __restrict__ dnc,
        int* __restrict__ knn, int* __restrict__ deg) {
    int b = blockIdx.y;
    int tid = threadIdx.x;
    int sub = tid >> 6, dn = tid & 63;   // 8 subs x 64 downs
    __shared__ float4 stage[NUP];                  // 32 KB AoS (x,y,z,ku)
    __shared__ unsigned long long Ubuf[1312];      // 10.25 KB union
    __shared__ int lcnt[64];
    float* sF = (float*)Ubuf;                      // phase-1 partials + thr
    unsigned long long* lst = Ubuf + 32;           // hit lists (above thr slots)

    float4 d = dnc[b * NDOWN + blockIdx.x * 64 + dn];
    float xd = d.x, yd = d.y, zd = d.z;
    int node = __float_as_int(d.w);
    float c1 = -2.0f * xd, c2 = -2.0f * yd, c3 = -2.0f * zd;
    float kd = fmaf(xd, xd, fmaf(yd, yd, zd * zd));

    const float4* U = upc + b * NUP;
    #pragma unroll
    for (int q = 0; q < 4; q++) {
        int i = q * 512 + tid;
        float4 u = U[i];
        u.w = fmaf(u.x, u.x, fmaf(u.y, u.y, u.z * u.z));
        stage[i] = u;
    }
    if (tid < 64) lcnt[tid] = 0;
    __syncthreads();

    // ---- phase 1: top-5 of t = ku - 2 u.d (med3 insert, 8 VALU + 1 b128)
    float L0 = 3.4e38f, L1 = 3.4e38f, L2 = 3.4e38f, L3 = 3.4e38f, L4 = 3.4e38f;
    const int j0 = sub * 256;
    #pragma unroll 4
    for (int j = j0; j < j0 + 256; ++j) {
        float4 c = stage[j];
        float t = fmaf(c.x, c1, fmaf(c.y, c2, fmaf(c.z, c3, c.w)));
        L4 = __builtin_amdgcn_fmed3f(t, L3, L4);
        L3 = __builtin_amdgcn_fmed3f(t, L2, L3);
        L2 = __builtin_amdgcn_fmed3f(t, L1, L2);
        L1 = __builtin_amdgcn_fmed3f(t, L0, L1);
        L0 = fminf(t, L0);
    }
    sF[(sub * MM + 0) * 64 + dn] = L0;
    sF[(sub * MM + 1) * 64 + dn] = L1;
    sF[(sub * MM + 2) * 64 + dn] = L2;
    sF[(sub * MM + 3) * 64 + dn] = L3;
    sF[(sub * MM + 4) * 64 + dn] = L4;
    __syncthreads();

    // ---- merge to the global 5th-smallest t per down
    if (sub == 0) {
        float F0 = 3.4e38f, F1 = 3.4e38f, F2 = 3.4e38f, F3 = 3.4e38f, F4 = 3.4e38f;
        for (int l = 0; l < 8; l++) {
            #pragma unroll
            for (int m = 0; m < MM; m++) {
                float v = sF[(l * MM + m) * 64 + dn];
                F4 = __builtin_amdgcn_fmed3f(v, F3, F4);
                F3 = __builtin_amdgcn_fmed3f(v, F2, F3);
                F2 = __builtin_amdgcn_fmed3f(v, F1, F2);
                F1 = __builtin_amdgcn_fmed3f(v, F0, F1);
                F0 = fminf(v, F0);
            }
        }
        sF[dn] = F4;   // T5 in t-space, Ubuf[0..32) (below lst region)
    }
    __syncthreads();
    float thr = sF[dn] + kd + 1e-3f;   // upper bound on exact 5th-smallest d2

    // ---- phase 2: exact d2 (bit-identical to prior kernel), inclusive gate
    #pragma unroll 4
    for (int j = j0; j < j0 + 256; ++j) {
        float4 c = stage[j];
        float dx = c.x - xd, dy = c.y - yd, dz = c.z - zd;
        float d2 = fmaf(dx, dx, fmaf(dy, dy, dz * dz));
        if (d2 <= thr) {
            unsigned long long key =
                ((unsigned long long)__float_as_uint(d2) << 32) |
                (unsigned long long)(unsigned)j;
            int s = atomicAdd(&lcnt[dn], 1);
            if (s < LSTW - 1) lst[dn * LSTW + s] = key;
        }
    }
    __syncthreads();

    // ---- final: exact (d2,idx) sort of the short list + outputs
    if (sub == 0) {
        unsigned long long fin[MM];
        #pragma unroll
        for (int m = 0; m < MM; m++) fin[m] = 0xFFFFFFFFFFFFFFFFull;
        int n = min(lcnt[dn], LSTW - 1);
        for (int s = 0; s < n; s++) {
            unsigned long long cand = lst[dn * LSTW + s];
            #pragma unroll
            for (int m = 0; m < MM; m++) {
                bool lt = cand < fin[m];
                unsigned long long lo = lt ? cand : fin[m];
                unsigned long long hi = lt ? fin[m] : cand;
                fin[m] = lo; cand = hi;
            }
        }
        int g = b * Nn + node;
        #pragma unroll
        for (int m = 0; m < MM; m++) {
            int lid = (int)(unsigned)(fin[m] & 0xFFFFFFFFull);
            knn[g * MM + m] = lid;                  // LOCAL up index
            atomicAdd(&deg[b * NUP + lid], 1);
        }
    }
}

// Kernel W: Wt[n][k] = bf16 of W-ext^T.
__global__ void wt_kernel(const float* __restrict__ W, const float* __restrict__ bias,
                          unsigned short* __restrict__ Wt) {
    int n = blockIdx.x;
    int k = threadIdx.x;
    Wt[n * KP + k] = bfc(W[(size_t)k * Hh + n]);
    if (k < KP - 256) {
        int kk = 256 + k;
        unsigned short v = 0;
        if (kk < 260)       v = bfc(W[(size_t)kk * Hh + n]);
        else if (kk == 260) v = bfc(bias[n]);
        Wt[n * KP + kk] = v;
    }
}

// Kernel B: feat GEMM via bf16 MFMA over DOWN rows only (up feats are never
// consumed: edges are down->up and gather overwrites up rows). 128 down-ranks
// x 128 cols per block; rows resolved via dnc node ids (ndid LDS).
__global__ void feat_mfma(const float* __restrict__ h, const float* __restrict__ sl,
                          const float* __restrict__ sc, const unsigned short* __restrict__ Wt,
                          const float4* __restrict__ dnc, float* __restrict__ out) {
    int b = blockIdx.z;
    int m0 = blockIdx.x * 128;   // down-rank tile base
    int n0 = blockIdx.y * 128;
    int tid = threadIdx.x;
    __shared__ unsigned short Al[128 * LDA];
    __shared__ unsigned short Bl[128 * LDA];
    __shared__ int ndid[128];
    int wid = tid >> 6, lane = tid & 63;
    int wm = (wid & 1) * 64, wn = (wid >> 1) * 64;
    int lm = lane & 15, quad = lane >> 4;
    if (tid < 128) ndid[tid] = __float_as_int(dnc[b * NDOWN + m0 + tid].w);
    v4f acc[4][4];
    #pragma unroll
    for (int i = 0; i < 4; i++)
        #pragma unroll
        for (int j = 0; j < 4; j++)
            acc[i][j] = (v4f){0.f, 0.f, 0.f, 0.f};
    const float* hb = h + (size_t)b * Nn * Hh;
    for (int t = 0; t < 9; t++) {
        int k0 = t * 32;
        __syncthreads();
        if (t < 8) {
            #pragma unroll
            for (int q = 0; q < 4; q++) {
                int e = q * 256 + tid;
                int row = e >> 3, kq = e & 7;
                float4 v = *(const float4*)(hb + (size_t)ndid[row] * Hh + k0 + kq * 4);
                ushort4 o = make_ushort4(bfc(v.x), bfc(v.y), bfc(v.z), bfc(v.w));
                *(ushort4*)(Al + row * LDA + kq * 4) = o;
            }
        } else if (tid < 128) {
            int row = tid;
            int g = b * Nn + ndid[row];
            unsigned short r[32];
            #pragma unroll
            for (int k = 0; k < 32; k++) r[k] = 0;
            r[0] = bfc(sl[(size_t)g * 3 + 0]);
            r[1] = bfc(sl[(size_t)g * 3 + 1]);
            r[2] = bfc(sl[(size_t)g * 3 + 2]);
            r[3] = bfc(sc[g]);
            r[4] = 0x3F80;  // 1.0 (bias column)
            #pragma unroll
            for (int q = 0; q < 8; q++)
                *(ushort4*)(Al + row * LDA + q * 4) =
                    make_ushort4(r[q * 4], r[q * 4 + 1], r[q * 4 + 2], r[q * 4 + 3]);
        }
        #pragma unroll
        for (int q = 0; q < 4; q++) {
            int e = q * 256 + tid;
            int n = e >> 3, kq = e & 7;
            ushort4 v = *(const ushort4*)(Wt + (size_t)(n0 + n) * KP + k0 + kq * 4);
            *(ushort4*)(Bl + n * LDA + kq * 4) = v;
        }
        __syncthreads();
        v8s af[4], bfr[4];
        #pragma unroll
        for (int i = 0; i < 4; i++)
            af[i] = *(const v8s*)(Al + (wm + i * 16 + lm) * LDA + quad * 8);
        #pragma unroll
        for (int j = 0; j < 4; j++)
            bfr[j] = *(const v8s*)(Bl + (wn + j * 16 + lm) * LDA + quad * 8);
        #pragma unroll
        for (int i = 0; i < 4; i++)
            #pragma unroll
            for (int j = 0; j < 4; j++)
                acc[i][j] = __builtin_amdgcn_mfma_f32_16x16x32_bf16(af[i], bfr[j], acc[i][j], 0, 0, 0);
    }
    #pragma unroll
    for (int i = 0; i < 4; i++) {
        #pragma unroll
        for (int r = 0; r < 4; r++) {
            int lrow = wm + i * 16 + quad * 4 + r;
            size_t base = ((size_t)b * Nn + ndid[lrow]) * Hh + n0 + wn + lm;
            #pragma unroll
            for (int j = 0; j < 4; j++)
                out[base + j * 16] = acc[i][j][r];
        }
    }
}

// CSR build: per-batch exclusive scan of deg -> rowptr (+ cursor copy).
__global__ __launch_bounds__(1024) void csr_scan(const int* __restrict__ deg,
                                                 int* __restrict__ rowptr,
                                                 int* __restrict__ cursor) {
    int b = blockIdx.x;
    int tid = threadIdx.x;
    int ln = tid & 63, wv = tid >> 6;
    __shared__ int wsum[16];
    int d0 = deg[b * NUP + 2 * tid], d1 = deg[b * NUP + 2 * tid + 1];
    int s = d0 + d1;
    int x = s;
    #pragma unroll
    for (int off = 1; off < 64; off <<= 1) {
        int y = __shfl_up(x, off);
        if (ln >= off) x += y;
    }
    if (ln == 63) wsum[wv] = x;
    __syncthreads();
    int base = 0;
    for (int w = 0; w < wv; w++) base += wsum[w];
    int excl = base + x - s;
    rowptr[b * (NUP + 1) + 2 * tid] = excl;
    rowptr[b * (NUP + 1) + 2 * tid + 1] = excl + d0;
    cursor[b * NUP + 2 * tid] = excl;
    cursor[b * NUP + 2 * tid + 1] = excl + d0;
    if (tid == 1023) rowptr[b * (NUP + 1) + NUP] = excl + s;
}

// CSR build: fill edge array (src = down node id; dst slot via local up idx).
__global__ void csr_fill(const float4* __restrict__ dnc, const int* __restrict__ knn,
                         int* __restrict__ cursor, int* __restrict__ edges) {
    int b = blockIdx.y;
    int r = blockIdx.x * 256 + threadIdx.x;
    int node = __float_as_int(dnc[b * NDOWN + r].w);
    int g = b * Nn + node;
    #pragma unroll
    for (int m = 0; m < MM; m++) {
        int un = knn[g * MM + m];   // local up index
        int slot = atomicAdd(&cursor[b * NUP + un], 1);
        edges[b * EPB + slot] = node;
    }
}

// Kernel D: gather-max. One wave per up node; lanes own 4 cols (float4).
// 4 accumulators -> 4 outstanding row loads. Also writes the up-node mask
// tail (1.0) -- lane 0.
__global__ void gather_kernel(const float4* __restrict__ upc, const int* __restrict__ rowptr,
                              const int* __restrict__ edges, float* __restrict__ out) {
    int b = blockIdx.y;
    int u = blockIdx.x * 4 + (threadIdx.x >> 6);
    int lane = threadIdx.x & 63;
    int node = __float_as_int(upc[b * NUP + u].w);
    int start = rowptr[b * (NUP + 1) + u];
    int end   = rowptr[b * (NUP + 1) + u + 1];
    const int* eb = edges + b * EPB;
    size_t rowbase = (size_t)b * Nn * Hh + (size_t)(lane << 2);
    float4 a0 = make_float4(-3.4e38f, -3.4e38f, -3.4e38f, -3.4e38f);
    float4 a1 = a0, a2 = a0, a3 = a0;
    int e = start;
    for (; e + 4 <= end; e += 4) {
        int s0 = eb[e], s1 = eb[e + 1], s2 = eb[e + 2], s3 = eb[e + 3];
        float4 v0 = *(const float4*)(out + rowbase + (size_t)s0 * Hh);
        float4 v1 = *(const float4*)(out + rowbase + (size_t)s1 * Hh);
        float4 v2 = *(const float4*)(out + rowbase + (size_t)s2 * Hh);
        float4 v3 = *(const float4*)(out + rowbase + (size_t)s3 * Hh);
        a0.x = fmaxf(a0.x, v0.x); a0.y = fmaxf(a0.y, v0.y);
        a0.z = fmaxf(a0.z, v0.z); a0.w = fmaxf(a0.w, v0.w);
        a1.x = fmaxf(a1.x, v1.x); a1.y = fmaxf(a1.y, v1.y);
        a1.z = fmaxf(a1.z, v1.z); a1.w = fmaxf(a1.w, v1.w);
        a2.x = fmaxf(a2.x, v2.x); a2.y = fmaxf(a2.y, v2.y);
        a2.z = fmaxf(a2.z, v2.z); a2.w = fmaxf(a2.w, v2.w);
        a3.x = fmaxf(a3.x, v3.x); a3.y = fmaxf(a3.y, v3.y);
        a3.z = fmaxf(a3.z, v3.z); a3.w = fmaxf(a3.w, v3.w);
    }
    for (; e < end; e++) {
        int s0 = eb[e];
        float4 v0 = *(const float4*)(out + rowbase + (size_t)s0 * Hh);
        a0.x = fmaxf(a0.x, v0.x); a0.y = fmaxf(a0.y, v0.y);
        a0.z = fmaxf(a0.z, v0.z); a0.w = fmaxf(a0.w, v0.w);
    }
    float4 r;
    r.x = fmaxf(fmaxf(a0.x, a1.x), fmaxf(a2.x, a3.x));
    r.y = fmaxf(fmaxf(a0.y, a1.y), fmaxf(a2.y, a3.y));
    r.z = fmaxf(fmaxf(a0.z, a1.z), fmaxf(a2.z, a3.z));
    r.w = fmaxf(fmaxf(a0.w, a1.w), fmaxf(a2.w, a3.w));
    if (start == end) r = make_float4(0.f, 0.f, 0.f, 0.f);
    *(float4*)(out + rowbase + (size_t)node * Hh) = r;
    if (lane == 0) out[(size_t)Bb * Nn * Hh + b * Nn + node] = 1.0f;
}

// Kernel E: zero down rows + down mask tail (exact grid over dnc).
__global__ void zero_down(const float4* __restrict__ dnc, float* __restrict__ out) {
    int b = blockIdx.y;
    int r = blockIdx.x * 4 + (threadIdx.x >> 6);
    int lane = threadIdx.x & 63;
    int node = __float_as_int(dnc[b * NDOWN + r].w);
    int g = b * Nn + node;
    *(float4*)(out + (size_t)g * Hh + (lane << 2)) = make_float4(0.f, 0.f, 0.f, 0.f);
    if (lane == 0) out[(size_t)Bb * Nn * Hh + g] = 0.0f;
}

extern "C" void kernel_launch(void* const* d_in, const int* in_sizes, int n_in,
                              void* d_out, int out_size, void* d_ws, size_t ws_size,
                              hipStream_t stream) {
    const float* h    = (const float*)d_in[0];
    const float* sl   = (const float*)d_in[1];
    const float* sc   = (const float*)d_in[2];
    const float* W    = (const float*)d_in[3];
    const float* bias = (const float*)d_in[4];

    char* ws = (char*)d_ws;
    int* knn  = (int*)ws;                 ws += (size_t)Bb * Nn * MM * sizeof(int);
    float4* upc = (float4*)ws;            ws += (size_t)Bb * NUP * sizeof(float4);
    float4* dnc = (float4*)ws;            ws += (size_t)Bb * NDOWN * sizeof(float4);
    unsigned short* Wt = (unsigned short*)ws; ws += (size_t)Hh * KP * sizeof(unsigned short);
    int* deg = (int*)ws;                  ws += (size_t)Bb * NUP * sizeof(int);
    int* cursor = (int*)ws;               ws += (size_t)Bb * NUP * sizeof(int);
    int* rowptr = (int*)ws;               ws += (size_t)Bb * (NUP + 1) * sizeof(int);
    int* edges = (int*)ws;                // B*EPB ints
    float* outf = (float*)d_out;

    dim3 blk(256);
    select_kernel<<<dim3(Bb), dim3(1024), 0, stream>>>(sc, sl, upc, dnc, deg);
    knn_brute<<<dim3(NDOWN / 64, Bb), dim3(512), 0, stream>>>(upc, dnc, knn, deg);
    csr_scan<<<dim3(Bb), dim3(1024), 0, stream>>>(deg, rowptr, cursor);
    csr_fill<<<dim3(NDOWN / 256, Bb), blk, 0, stream>>>(dnc, knn, cursor, edges);
    wt_kernel<<<dim3(Hh), blk, 0, stream>>>(W, bias, Wt);
    feat_mfma<<<dim3(NDOWN / 128, 2, Bb), blk, 0, stream>>>(h, sl, sc, Wt, dnc, outf);
    gather_kernel<<<dim3(NUP / 4, Bb), blk, 0, stream>>>(upc, rowptr, edges, outf);
    zero_down<<<dim3(NDOWN / 4, Bb), blk, 0, stream>>>(dnc, outf);
}

// Round 10
// 259.416 us; speedup vs baseline: 1.3495x; 1.0140x over previous
//
#include <hip/hip_runtime.h>

#define Bb 8
#define Nn 8192
#define Hh 256
#define NUP 2048
#define NDOWN (Nn - NUP)
#define MM 5
#define EPB (NDOWN * MM)   // edges per batch = 30720
#define KP 288             // padded K for the feat GEMM (256 h + sl,score,1,pad)
#define LDA 36             // LDS row stride (bf16) for A/B tiles
#define LSTW 24            // hit-list stride (u64) per down (23 usable)

typedef short v8s __attribute__((ext_vector_type(8)));
typedef float v4f __attribute__((ext_vector_type(4)));

// fp32 -> bf16 round-to-nearest-even
__device__ __forceinline__ unsigned short bfc(float f) {
    unsigned u = __float_as_uint(f);
    return (unsigned short)((u + 0x7FFFu + ((u >> 16) & 1u)) >> 16);
}

// Find the bin (descending order) where the kth-largest element lands.
template <int NB>
__device__ void find_kth_bin(const int* hist, int kth, int tid,
                             int* wsumA, int* res, int* out_bin, int* out_cntgt) {
    constexpr int PER = NB / 1024;
    int ln = tid & 63, wv = tid >> 6;
    int b0 = NB - 1 - PER * tid;
    int c0 = hist[b0];
    int c1 = (PER == 2) ? hist[b0 - 1] : 0;
    int tot = c0 + c1;
    int x = tot;
    #pragma unroll
    for (int off = 1; off < 64; off <<= 1) {
        int y = __shfl_up(x, off);
        if (ln >= off) x += y;
    }
    if (ln == 63) wsumA[wv] = x;
    __syncthreads();
    int wbase = 0;
    for (int w = 0; w < wv; w++) wbase += wsumA[w];
    int excl = wbase + x - tot;
    if (excl < kth && excl + c0 >= kth) { res[0] = b0; res[1] = excl; }
    else if (PER == 2 && excl + c0 < kth && excl + c0 + c1 >= kth) { res[0] = b0 - 1; res[1] = excl + c0; }
    __syncthreads();
    *out_bin = res[0];
    *out_cntgt = res[1];
}

// Kernel A: exact top-NUP selection via 3-level radix select. Scores cached in
// registers; single-pass stable compaction (two block scans); sl loaded as 6
// aligned float4 per thread (96B contiguous).
__global__ __launch_bounds__(1024) void select_kernel(
        const float* __restrict__ scores, const float* __restrict__ sl,
        float4* __restrict__ upc, float4* __restrict__ dnc,
        int* __restrict__ deg) {
    int b = blockIdx.x;
    int tid = threadIdx.x;
    int ln = tid & 63, wv = tid >> 6;
    __shared__ int hist[2048];
    __shared__ int wsumA[16];
    __shared__ int res[2];
    const float* s = scores + (size_t)b * Nn;

    deg[b * NUP + tid] = 0;
    deg[b * NUP + 1024 + tid] = 0;

    float4 sa = *(const float4*)(s + tid * 8);
    float4 sb = *(const float4*)(s + tid * 8 + 4);
    unsigned ub[8] = {__float_as_uint(sa.x), __float_as_uint(sa.y),
                      __float_as_uint(sa.z), __float_as_uint(sa.w),
                      __float_as_uint(sb.x), __float_as_uint(sb.y),
                      __float_as_uint(sb.z), __float_as_uint(sb.w)};

    hist[tid] = 0; hist[tid + 1024] = 0;
    __syncthreads();
    #pragma unroll
    for (int k = 0; k < 8; k++) atomicAdd(&hist[ub[k] >> 21], 1);
    __syncthreads();
    int B1, gt1;
    find_kth_bin<2048>(hist, NUP, tid, wsumA, res, &B1, &gt1);
    int slots1 = NUP - gt1;

    hist[tid] = 0; hist[tid + 1024] = 0;
    __syncthreads();
    #pragma unroll
    for (int k = 0; k < 8; k++)
        if ((int)(ub[k] >> 21) == B1) atomicAdd(&hist[(ub[k] >> 10) & 0x7FF], 1);
    __syncthreads();
    int B2, gt2;
    find_kth_bin<2048>(hist, slots1, tid, wsumA, res, &B2, &gt2);
    int slots2 = slots1 - gt2;
    unsigned hi22 = ((unsigned)B1 << 11) | (unsigned)B2;

    hist[tid] = 0; hist[tid + 1024] = 0;
    __syncthreads();
    #pragma unroll
    for (int k = 0; k < 8; k++)
        if ((ub[k] >> 10) == hi22) atomicAdd(&hist[ub[k] & 0x3FF], 1);
    __syncthreads();
    int B3, gt3;
    find_kth_bin<1024>(hist, slots2, tid, wsumA, res, &B3, &gt3);
    int slots_eq = slots2 - gt3;
    unsigned T = (hi22 << 10) | (unsigned)B3;

    // ---- single-pass stable compaction ----
    int eqc = 0;
    #pragma unroll
    for (int k = 0; k < 8; k++) eqc += (ub[k] == T) ? 1 : 0;
    int x = eqc;
    #pragma unroll
    for (int off = 1; off < 64; off <<= 1) {
        int y = __shfl_up(x, off);
        if (ln >= off) x += y;
    }
    if (ln == 63) wsumA[wv] = x;
    __syncthreads();
    int eqb = x - eqc;
    for (int w = 0; w < wv; w++) eqb += wsumA[w];
    __syncthreads();   // wsumA reusable

    int upcnt = 0, eqrun = 0, upf = 0;
    #pragma unroll
    for (int k = 0; k < 8; k++) {
        bool eq = (ub[k] == T);
        bool up = (ub[k] > T) || (eq && (eqb + eqrun) < slots_eq);
        eqrun += eq ? 1 : 0;
        upf |= (up ? 1 : 0) << k;
        upcnt += up ? 1 : 0;
    }
    x = upcnt;
    #pragma unroll
    for (int off = 1; off < 64; off <<= 1) {
        int y = __shfl_up(x, off);
        if (ln >= off) x += y;
    }
    if (ln == 63) wsumA[wv] = x;
    __syncthreads();
    int upb = x - upcnt;
    for (int w = 0; w < wv; w++) upb += wsumA[w];

    // ---- vectorized sl read: 96 contiguous bytes per thread (16B-aligned)
    const float* slb = sl + ((size_t)b * Nn + (size_t)tid * 8) * 3;
    float fb[24];
    *(float4*)(fb + 0)  = *(const float4*)(slb + 0);
    *(float4*)(fb + 4)  = *(const float4*)(slb + 4);
    *(float4*)(fb + 8)  = *(const float4*)(slb + 8);
    *(float4*)(fb + 12) = *(const float4*)(slb + 12);
    *(float4*)(fb + 16) = *(const float4*)(slb + 16);
    *(float4*)(fb + 20) = *(const float4*)(slb + 20);

    int uprun = 0;
    #pragma unroll
    for (int k = 0; k < 8; k++) {
        int node = tid * 8 + k;
        float4 c;
        c.x = fb[3 * k]; c.y = fb[3 * k + 1]; c.z = fb[3 * k + 2];
        c.w = __int_as_float(node);
        bool up = (upf >> k) & 1;
        if (up) upc[b * NUP + upb + uprun] = c;
        else    dnc[b * NDOWN + node - (upb + uprun)] = c;
        uprun += up ? 1 : 0;
    }
}

// Kernel C: exact 5-NN, brute force, two-phase. 512 threads = 64 downs
// (lanes) x 8 candidate slices (waves). Ups staged AoS (x,y,z,|u|^2) -> one
// ds_read_b128 per candidate. Phase 1 ranks by the expanded metric
// t = |u|^2 - 2 u.d (3 FMA) with med3 top-5 -> exact 5th-smallest t (T5t).
// Phase 2 gates on t <= T5t + 1e-3 (3 FMA + cmp common path): at most 4
// candidates have d2 < D5 and |t-(d2-kd)| <= ~4e-5 << 1e-3, so every true
// top-5 (and tie) candidate passes -> superset hit list. Hits compute the
// BIT-IDENTICAL d2 of prior rounds; final exact (d2, local idx) sort =
// identical output (upc node-ordered => local-idx == node-id tie-break).
__global__ __launch_bounds__(512) void knn_brute(
        const float4* __restrict__ upc, const float4* __restrict__ dnc,
        int* __restrict__ knn, int* __restrict__ deg) {
    int b = blockIdx.y;
    int tid = threadIdx.x;
    int sub = tid >> 6, dn = tid & 63;   // 8 subs x 64 downs
    __shared__ float4 stage[NUP];                  // 32 KB AoS (x,y,z,ku)
    __shared__ unsigned long long Ubuf[32 + 64 * LSTW];  // 12.25 KB union
    __shared__ int lcnt[64];
    float* sF = (float*)Ubuf;                      // phase-1 partials + T5t
    unsigned long long* lst = Ubuf + 32;           // hit lists (above T5t slots)

    float4 d = dnc[b * NDOWN + blockIdx.x * 64 + dn];
    float xd = d.x, yd = d.y, zd = d.z;
    int node = __float_as_int(d.w);
    float c1 = -2.0f * xd, c2 = -2.0f * yd, c3 = -2.0f * zd;

    const float4* U = upc + b * NUP;
    #pragma unroll
    for (int q = 0; q < 4; q++) {
        int i = q * 512 + tid;
        float4 u = U[i];
        u.w = fmaf(u.x, u.x, fmaf(u.y, u.y, u.z * u.z));
        stage[i] = u;
    }
    if (tid < 64) lcnt[tid] = 0;
    __syncthreads();

    // ---- phase 1: top-5 of t = ku - 2 u.d (med3 insert, 8 VALU + 1 b128)
    float L0 = 3.4e38f, L1 = 3.4e38f, L2 = 3.4e38f, L3 = 3.4e38f, L4 = 3.4e38f;
    const int j0 = sub * 256;
    #pragma unroll 4
    for (int j = j0; j < j0 + 256; ++j) {
        float4 c = stage[j];
        float t = fmaf(c.x, c1, fmaf(c.y, c2, fmaf(c.z, c3, c.w)));
        L4 = __builtin_amdgcn_fmed3f(t, L3, L4);
        L3 = __builtin_amdgcn_fmed3f(t, L2, L3);
        L2 = __builtin_amdgcn_fmed3f(t, L1, L2);
        L1 = __builtin_amdgcn_fmed3f(t, L0, L1);
        L0 = fminf(t, L0);
    }
    sF[(sub * MM + 0) * 64 + dn] = L0;
    sF[(sub * MM + 1) * 64 + dn] = L1;
    sF[(sub * MM + 2) * 64 + dn] = L2;
    sF[(sub * MM + 3) * 64 + dn] = L3;
    sF[(sub * MM + 4) * 64 + dn] = L4;
    __syncthreads();

    // ---- merge to the global 5th-smallest t per down
    if (sub == 0) {
        float F0 = 3.4e38f, F1 = 3.4e38f, F2 = 3.4e38f, F3 = 3.4e38f, F4 = 3.4e38f;
        for (int l = 0; l < 8; l++) {
            #pragma unroll
            for (int m = 0; m < MM; m++) {
                float v = sF[(l * MM + m) * 64 + dn];
                F4 = __builtin_amdgcn_fmed3f(v, F3, F4);
                F3 = __builtin_amdgcn_fmed3f(v, F2, F3);
                F2 = __builtin_amdgcn_fmed3f(v, F1, F2);
                F1 = __builtin_amdgcn_fmed3f(v, F0, F1);
                F0 = fminf(v, F0);
            }
        }
        sF[dn] = F4;   // T5t, Ubuf[0..32) (below lst region)
    }
    __syncthreads();
    float tthr = sF[dn] + 1e-3f;   // covers |t - (d2-kd)| rounding (<=~4e-5)

    // ---- phase 2: t-gated (3 FMA + cmp); hits compute exact d2 key
    #pragma unroll 4
    for (int j = j0; j < j0 + 256; ++j) {
        float4 c = stage[j];
        float t = fmaf(c.x, c1, fmaf(c.y, c2, fmaf(c.z, c3, c.w)));
        if (t <= tthr) {
            float dx = c.x - xd, dy = c.y - yd, dz = c.z - zd;
            float d2 = fmaf(dx, dx, fmaf(dy, dy, dz * dz));
            unsigned long long key =
                ((unsigned long long)__float_as_uint(d2) << 32) |
                (unsigned long long)(unsigned)j;
            int s = atomicAdd(&lcnt[dn], 1);
            if (s < LSTW - 1) lst[dn * LSTW + s] = key;
        }
    }
    __syncthreads();

    // ---- final: exact (d2,idx) sort of the short list + outputs
    if (sub == 0) {
        unsigned long long fin[MM];
        #pragma unroll
        for (int m = 0; m < MM; m++) fin[m] = 0xFFFFFFFFFFFFFFFFull;
        int n = min(lcnt[dn], LSTW - 1);
        for (int s = 0; s < n; s++) {
            unsigned long long cand = lst[dn * LSTW + s];
            #pragma unroll
            for (int m = 0; m < MM; m++) {
                bool lt = cand < fin[m];
                unsigned long long lo = lt ? cand : fin[m];
                unsigned long long hi = lt ? fin[m] : cand;
                fin[m] = lo; cand = hi;
            }
        }
        int g = b * Nn + node;
        #pragma unroll
        for (int m = 0; m < MM; m++) {
            int lid = (int)(unsigned)(fin[m] & 0xFFFFFFFFull);
            knn[g * MM + m] = lid;                  // LOCAL up index
            atomicAdd(&deg[b * NUP + lid], 1);
        }
    }
}

// Kernel W: Wt[n][k] = bf16 of W-ext^T.
__global__ void wt_kernel(const float* __restrict__ W, const float* __restrict__ bias,
                          unsigned short* __restrict__ Wt) {
    int n = blockIdx.x;
    int k = threadIdx.x;
    Wt[n * KP + k] = bfc(W[(size_t)k * Hh + n]);
    if (k < KP - 256) {
        int kk = 256 + k;
        unsigned short v = 0;
        if (kk < 260)       v = bfc(W[(size_t)kk * Hh + n]);
        else if (kk == 260) v = bfc(bias[n]);
        Wt[n * KP + kk] = v;
    }
}

// Kernel B: feat GEMM via bf16 MFMA over DOWN rows only (up feats are never
// consumed: edges are down->up and gather overwrites up rows). 128 down-ranks
// x 128 cols per block; rows resolved via dnc node ids (ndid LDS).
__global__ void feat_mfma(const float* __restrict__ h, const float* __restrict__ sl,
                          const float* __restrict__ sc, const unsigned short* __restrict__ Wt,
                          const float4* __restrict__ dnc, float* __restrict__ out) {
    int b = blockIdx.z;
    int m0 = blockIdx.x * 128;   // down-rank tile base
    int n0 = blockIdx.y * 128;
    int tid = threadIdx.x;
    __shared__ unsigned short Al[128 * LDA];
    __shared__ unsigned short Bl[128 * LDA];
    __shared__ int ndid[128];
    int wid = tid >> 6, lane = tid & 63;
    int wm = (wid & 1) * 64, wn = (wid >> 1) * 64;
    int lm = lane & 15, quad = lane >> 4;
    if (tid < 128) ndid[tid] = __float_as_int(dnc[b * NDOWN + m0 + tid].w);
    v4f acc[4][4];
    #pragma unroll
    for (int i = 0; i < 4; i++)
        #pragma unroll
        for (int j = 0; j < 4; j++)
            acc[i][j] = (v4f){0.f, 0.f, 0.f, 0.f};
    const float* hb = h + (size_t)b * Nn * Hh;
    for (int t = 0; t < 9; t++) {
        int k0 = t * 32;
        __syncthreads();
        if (t < 8) {
            #pragma unroll
            for (int q = 0; q < 4; q++) {
                int e = q * 256 + tid;
                int row = e >> 3, kq = e & 7;
                float4 v = *(const float4*)(hb + (size_t)ndid[row] * Hh + k0 + kq * 4);
                ushort4 o = make_ushort4(bfc(v.x), bfc(v.y), bfc(v.z), bfc(v.w));
                *(ushort4*)(Al + row * LDA + kq * 4) = o;
            }
        } else if (tid < 128) {
            int row = tid;
            int g = b * Nn + ndid[row];
            unsigned short r[32];
            #pragma unroll
            for (int k = 0; k < 32; k++) r[k] = 0;
            r[0] = bfc(sl[(size_t)g * 3 + 0]);
            r[1] = bfc(sl[(size_t)g * 3 + 1]);
            r[2] = bfc(sl[(size_t)g * 3 + 2]);
            r[3] = bfc(sc[g]);
            r[4] = 0x3F80;  // 1.0 (bias column)
            #pragma unroll
            for (int q = 0; q < 8; q++)
                *(ushort4*)(Al + row * LDA + q * 4) =
                    make_ushort4(r[q * 4], r[q * 4 + 1], r[q * 4 + 2], r[q * 4 + 3]);
        }
        #pragma unroll
        for (int q = 0; q < 4; q++) {
            int e = q * 256 + tid;
            int n = e >> 3, kq = e & 7;
            ushort4 v = *(const ushort4*)(Wt + (size_t)(n0 + n) * KP + k0 + kq * 4);
            *(ushort4*)(Bl + n * LDA + kq * 4) = v;
        }
        __syncthreads();
        v8s af[4], bfr[4];
        #pragma unroll
        for (int i = 0; i < 4; i++)
            af[i] = *(const v8s*)(Al + (wm + i * 16 + lm) * LDA + quad * 8);
        #pragma unroll
        for (int j = 0; j < 4; j++)
            bfr[j] = *(const v8s*)(Bl + (wn + j * 16 + lm) * LDA + quad * 8);
        #pragma unroll
        for (int i = 0; i < 4; i++)
            #pragma unroll
            for (int j = 0; j < 4; j++)
                acc[i][j] = __builtin_amdgcn_mfma_f32_16x16x32_bf16(af[i], bfr[j], acc[i][j], 0, 0, 0);
    }
    #pragma unroll
    for (int i = 0; i < 4; i++) {
        #pragma unroll
        for (int r = 0; r < 4; r++) {
            int lrow = wm + i * 16 + quad * 4 + r;
            size_t base = ((size_t)b * Nn + ndid[lrow]) * Hh + n0 + wn + lm;
            #pragma unroll
            for (int j = 0; j < 4; j++)
                out[base + j * 16] = acc[i][j][r];
        }
    }
}

// CSR build: per-batch exclusive scan of deg -> rowptr (+ cursor copy).
__global__ __launch_bounds__(1024) void csr_scan(const int* __restrict__ deg,
                                                 int* __restrict__ rowptr,
                                                 int* __restrict__ cursor) {
    int b = blockIdx.x;
    int tid = threadIdx.x;
    int ln = tid & 63, wv = tid >> 6;
    __shared__ int wsum[16];
    int d0 = deg[b * NUP + 2 * tid], d1 = deg[b * NUP + 2 * tid + 1];
    int s = d0 + d1;
    int x = s;
    #pragma unroll
    for (int off = 1; off < 64; off <<= 1) {
        int y = __shfl_up(x, off);
        if (ln >= off) x += y;
    }
    if (ln == 63) wsum[wv] = x;
    __syncthreads();
    int base = 0;
    for (int w = 0; w < wv; w++) base += wsum[w];
    int excl = base + x - s;
    rowptr[b * (NUP + 1) + 2 * tid] = excl;
    rowptr[b * (NUP + 1) + 2 * tid + 1] = excl + d0;
    cursor[b * NUP + 2 * tid] = excl;
    cursor[b * NUP + 2 * tid + 1] = excl + d0;
    if (tid == 1023) rowptr[b * (NUP + 1) + NUP] = excl + s;
}

// CSR build: fill edge array (src = down node id; dst slot via local up idx).
__global__ void csr_fill(const float4* __restrict__ dnc, const int* __restrict__ knn,
                         int* __restrict__ cursor, int* __restrict__ edges) {
    int b = blockIdx.y;
    int r = blockIdx.x * 256 + threadIdx.x;
    int node = __float_as_int(dnc[b * NDOWN + r].w);
    int g = b * Nn + node;
    #pragma unroll
    for (int m = 0; m < MM; m++) {
        int un = knn[g * MM + m];   // local up index
        int slot = atomicAdd(&cursor[b * NUP + un], 1);
        edges[b * EPB + slot] = node;
    }
}

// Kernel D: gather-max. One wave per up node; lanes own 4 cols (float4).
// 4 accumulators -> 4 outstanding row loads. Also writes the up-node mask
// tail (1.0). MUST run fully before zero_down (reads down rows zero_down
// destroys) -- separate dispatches for ordering.
__global__ void gather_kernel(const float4* __restrict__ upc, const int* __restrict__ rowptr,
                              const int* __restrict__ edges, float* __restrict__ out) {
    int b = blockIdx.y;
    int u = blockIdx.x * 4 + (threadIdx.x >> 6);
    int lane = threadIdx.x & 63;
    int node = __float_as_int(upc[b * NUP + u].w);
    int start = rowptr[b * (NUP + 1) + u];
    int end   = rowptr[b * (NUP + 1) + u + 1];
    const int* eb = edges + b * EPB;
    size_t rowbase = (size_t)b * Nn * Hh + (size_t)(lane << 2);
    float4 a0 = make_float4(-3.4e38f, -3.4e38f, -3.4e38f, -3.4e38f);
    float4 a1 = a0, a2 = a0, a3 = a0;
    int e = start;
    for (; e + 4 <= end; e += 4) {
        int s0 = eb[e], s1 = eb[e + 1], s2 = eb[e + 2], s3 = eb[e + 3];
        float4 v0 = *(const float4*)(out + rowbase + (size_t)s0 * Hh);
        float4 v1 = *(const float4*)(out + rowbase + (size_t)s1 * Hh);
        float4 v2 = *(const float4*)(out + rowbase + (size_t)s2 * Hh);
        float4 v3 = *(const float4*)(out + rowbase + (size_t)s3 * Hh);
        a0.x = fmaxf(a0.x, v0.x); a0.y = fmaxf(a0.y, v0.y);
        a0.z = fmaxf(a0.z, v0.z); a0.w = fmaxf(a0.w, v0.w);
        a1.x = fmaxf(a1.x, v1.x); a1.y = fmaxf(a1.y, v1.y);
        a1.z = fmaxf(a1.z, v1.z); a1.w = fmaxf(a1.w, v1.w);
        a2.x = fmaxf(a2.x, v2.x); a2.y = fmaxf(a2.y, v2.y);
        a2.z = fmaxf(a2.z, v2.z); a2.w = fmaxf(a2.w, v2.w);
        a3.x = fmaxf(a3.x, v3.x); a3.y = fmaxf(a3.y, v3.y);
        a3.z = fmaxf(a3.z, v3.z); a3.w = fmaxf(a3.w, v3.w);
    }
    for (; e < end; e++) {
        int s0 = eb[e];
        float4 v0 = *(const float4*)(out + rowbase + (size_t)s0 * Hh);
        a0.x = fmaxf(a0.x, v0.x); a0.y = fmaxf(a0.y, v0.y);
        a0.z = fmaxf(a0.z, v0.z); a0.w = fmaxf(a0.w, v0.w);
    }
    float4 r;
    r.x = fmaxf(fmaxf(a0.x, a1.x), fmaxf(a2.x, a3.x));
    r.y = fmaxf(fmaxf(a0.y, a1.y), fmaxf(a2.y, a3.y));
    r.z = fmaxf(fmaxf(a0.z, a1.z), fmaxf(a2.z, a3.z));
    r.w = fmaxf(fmaxf(a0.w, a1.w), fmaxf(a2.w, a3.w));
    if (start == end) r = make_float4(0.f, 0.f, 0.f, 0.f);
    *(float4*)(out + rowbase + (size_t)node * Hh) = r;
    if (lane == 0) out[(size_t)Bb * Nn * Hh + b * Nn + node] = 1.0f;
}

// Kernel E: zero down rows + down mask tail (exact grid over dnc).
__global__ void zero_down(const float4* __restrict__ dnc, float* __restrict__ out) {
    int b = blockIdx.y;
    int r = blockIdx.x * 4 + (threadIdx.x >> 6);
    int lane = threadIdx.x & 63;
    int node = __float_as_int(dnc[b * NDOWN + r].w);
    int g = b * Nn + node;
    *(float4*)(out + (size_t)g * Hh + (lane << 2)) = make_float4(0.f, 0.f, 0.f, 0.f);
    if (lane == 0) out[(size_t)Bb * Nn * Hh + g] = 0.0f;
}

extern "C" void kernel_launch(void* const* d_in, const int* in_sizes, int n_in,
                              void* d_out, int out_size, void* d_ws, size_t ws_size,
                              hipStream_t stream) {
    const float* h    = (const float*)d_in[0];
    const float* sl   = (const float*)d_in[1];
    const float* sc   = (const float*)d_in[2];
    const float* W    = (const float*)d_in[3];
    const float* bias = (const float*)d_in[4];

    char* ws = (char*)d_ws;
    int* knn  = (int*)ws;                 ws += (size_t)Bb * Nn * MM * sizeof(int);
    float4* upc = (float4*)ws;            ws += (size_t)Bb * NUP * sizeof(float4);
    float4* dnc = (float4*)ws;            ws += (size_t)Bb * NDOWN * sizeof(float4);
    unsigned short* Wt = (unsigned short*)ws; ws += (size_t)Hh * KP * sizeof(unsigned short);
    int* deg = (int*)ws;                  ws += (size_t)Bb * NUP * sizeof(int);
    int* cursor = (int*)ws;               ws += (size_t)Bb * NUP * sizeof(int);
    int* rowptr = (int*)ws;               ws += (size_t)Bb * (NUP + 1) * sizeof(int);
    int* edges = (int*)ws;                // B*EPB ints
    float* outf = (float*)d_out;

    dim3 blk(256);
    select_kernel<<<dim3(Bb), dim3(1024), 0, stream>>>(sc, sl, upc, dnc, deg);
    knn_brute<<<dim3(NDOWN / 64, Bb), dim3(512), 0, stream>>>(upc, dnc, knn, deg);
    csr_scan<<<dim3(Bb), dim3(1024), 0, stream>>>(deg, rowptr, cursor);
    csr_fill<<<dim3(NDOWN / 256, Bb), blk, 0, stream>>>(dnc, knn, cursor, edges);
    wt_kernel<<<dim3(Hh), blk, 0, stream>>>(W, bias, Wt);
    feat_mfma<<<dim3(NDOWN / 128, 2, Bb), blk, 0, stream>>>(h, sl, sc, Wt, dnc, outf);
    gather_kernel<<<dim3(NUP / 4, Bb), blk, 0, stream>>>(upc, rowptr, edges, outf);
    zero_down<<<dim3(NDOWN / 4, Bb), blk, 0, stream>>>(dnc, outf);
}